// Round 5
// baseline (5362.688 us; speedup 1.0000x reference)
//
#include <hip/hip_runtime.h>

typedef unsigned short u16;

#define BB 2
#define SS 2048
#define DD 1024
#define HH 16
#define KK 512

// workspace layout (bytes) — total ~80.1 MB, all fp32
#define OFF_SCAL  ((size_t)0)                          // accbuf[2] f32, itemp[2] f32
#define OFF_QH    ((size_t)256)                        // 4096x4096 f32 (Q|K|V|Gpre) = 64 MB
#define OFF_AO    (OFF_QH + (size_t)4096 * 4096 * 4)   // 4096x1024 f32 attn out = 16 MB

// order-preserving float->uint key
__device__ __forceinline__ unsigned fkey(float f) {
    unsigned u = __float_as_uint(f);
    return (u & 0x80000000u) ? ~u : (u | 0x80000000u);
}

// ---------------------------------------------------------------------------
// 1) adaptive temperature partial: acc[b] = sum_s (x[b,s,:] . Wt)
// ---------------------------------------------------------------------------
__global__ __launch_bounds__(256) void temp_partial(const float* x, const float* Wt,
                                                    float* accbuf) {
    int b = blockIdx.x >> 5, ch = blockIdx.x & 31;
    float a = 0.f;
    for (int si = 0; si < 64; si++) {
        int s = ch * 64 + si;
        const float* xr = x + ((size_t)(b * SS + s)) * DD;
#pragma unroll
        for (int k = 0; k < 4; k++) {
            int c = threadIdx.x + k * 256;
            a += xr[c] * Wt[c];
        }
    }
    for (int o = 32; o; o >>= 1) a += __shfl_xor(a, o);
    __shared__ float red[4];
    if ((threadIdx.x & 63) == 0) red[threadIdx.x >> 6] = a;
    __syncthreads();
    if (threadIdx.x == 0) atomicAdd(&accbuf[b], red[0] + red[1] + red[2] + red[3]);
}

__global__ void temp_final(const float* accbuf, const float* bt, float* itemp) {
    int t = threadIdx.x;
    if (t < BB) {
        float v = accbuf[t] / (float)SS + bt[0];
        float tmp = 1.f / (1.f + __expf(-v)) + 0.5f;
        itemp[t] = 1.f / tmp;
    }
}

// ---------------------------------------------------------------------------
// 2) scalar QKVG GEMM: Qh[m][n'] = X[m][:] . W*[:, n] + b   (n' = 4096 concat)
// ---------------------------------------------------------------------------
__global__ __launch_bounds__(256) void gemm_qkvg_s(
        const float* X, const float* Wq, const float* Wk, const float* Wv, const float* Wg,
        const float* bq, const float* bk, const float* bv, const float* bg, float* Qh) {
    __shared__ float xs[64][65];
    int tid = threadIdx.x;
    int nglob = blockIdx.x * 256 + tid;      // 0..4095 (mat uniform per block)
    int mat = nglob >> 10, n = nglob & 1023;
    const float* W  = (mat == 0) ? Wq : (mat == 1) ? Wk : (mat == 2) ? Wv : Wg;
    const float* bp = (mat == 0) ? bq : (mat == 1) ? bk : (mat == 2) ? bv : bg;
    int m0 = blockIdx.y * 64;
    float acc[64];
#pragma unroll
    for (int i = 0; i < 64; i++) acc[i] = 0.f;
    int r = tid >> 2, c0 = (tid & 3) * 16;
    for (int k0 = 0; k0 < 1024; k0 += 64) {
        __syncthreads();
#pragma unroll
        for (int u = 0; u < 16; u++)
            xs[r][c0 + u] = X[(size_t)(m0 + r) * 1024 + k0 + c0 + u];
        __syncthreads();
        for (int kk = 0; kk < 64; kk++) {
            float w = W[(size_t)(k0 + kk) * 1024 + n];
#pragma unroll
            for (int mm = 0; mm < 64; mm++) acc[mm] += xs[mm][kk] * w;
        }
    }
    float bias = bp[n];
    for (int mm = 0; mm < 64; mm++)
        Qh[(size_t)(m0 + mm) * 4096 + nglob] = acc[mm] + bias;
}

// ---------------------------------------------------------------------------
// 3) normalize q,k (per-head L2) in place in Qh
// ---------------------------------------------------------------------------
__global__ __launch_bounds__(256) void norm_qk(float* Qh) {
    int wid = threadIdx.x >> 6, lane = threadIdx.x & 63;
    int idx = blockIdx.x * 4 + wid;          // (token, head), 65536 total
    int token = idx >> 4, h = idx & 15;
    float* rowp = Qh + (size_t)token * 4096 + h * 64;
    float q = rowp[lane];
    float k = rowp[1024 + lane];
    float sq = q * q, sk = k * k;
    for (int o = 32; o; o >>= 1) { sq += __shfl_xor(sq, o); sk += __shfl_xor(sk, o); }
    float qd = fmaxf(sqrtf(sq), 1e-12f), kd = fmaxf(sqrtf(sk), 1e-12f);
    rowp[lane] = q / qd;
    rowp[1024 + lane] = k / kd;
}

// ---------------------------------------------------------------------------
// 4) scalar attention, 16 q-rows per block. Scores -> LDS; per-wave exact
//    32-bit top-512 threshold; exp; scalar PV. No MFMA.
// ---------------------------------------------------------------------------
__global__ __launch_bounds__(256) void attn16(const float* Qh, const float* itemp, float* ao) {
    __shared__ float qs[16][64];      // 4 KB
    __shared__ float sc[16][2048];    // 128 KB
    __shared__ float zs[16];
    int tid = threadIdx.x, wid = tid >> 6, lane = tid & 63;
    int bh = blockIdx.x >> 7, qt = blockIdx.x & 127;
    int b = bh >> 4, h = bh & 15;
    const float* base = Qh + (size_t)(b * SS) * 4096;
    const float* qbase = base + (size_t)(qt * 16) * 4096 + h * 64;

    // load 16x64 q block
#pragma unroll
    for (int i = 0; i < 4; i++) {
        int idx = tid + i * 256;
        qs[idx >> 6][idx & 63] = qbase[(size_t)(idx >> 6) * 4096 + (idx & 63)];
    }
    __syncthreads();
    float it = itemp[b];

    // scores: thread t handles cols {t, t+256, ...}
    for (int jj = 0; jj < 8; jj++) {
        int j = tid + jj * 256;
        const float* krow = base + (size_t)j * 4096 + 1024 + h * 64;
        float acc[16];
#pragma unroll
        for (int r2 = 0; r2 < 16; r2++) acc[r2] = 0.f;
        for (int d0 = 0; d0 < 64; d0 += 8) {
            float kr[8];
#pragma unroll
            for (int u = 0; u < 8; u++) kr[u] = krow[d0 + u];
#pragma unroll
            for (int r2 = 0; r2 < 16; r2++)
#pragma unroll
                for (int u = 0; u < 8; u++) acc[r2] += qs[r2][d0 + u] * kr[u];
        }
#pragma unroll
        for (int r2 = 0; r2 < 16; r2++) sc[r2][j] = acc[r2] * it;
    }
    __syncthreads();

    // per-wave: rows wid*4 .. wid*4+3; lane covers cols {c*64 + lane}
    for (int rr = 0; rr < 4; rr++) {
        int row = wid * 4 + rr;
        float s[32];
        unsigned key[32];
#pragma unroll
        for (int c = 0; c < 32; c++) {
            s[c] = sc[row][c * 64 + lane];
            key[c] = fkey(s[c]);
        }
        float m = s[0];
#pragma unroll
        for (int c = 1; c < 32; c++) m = fmaxf(m, s[c]);
        for (int o = 32; o; o >>= 1) m = fmaxf(m, __shfl_xor(m, o));
        // exact 32-bit threshold: largest P with |{key >= P}| >= 512
        unsigned P = 0u;
        for (int bit = 31; bit >= 0; bit--) {
            unsigned cand = P | (1u << bit);
            int cnt = 0;
#pragma unroll
            for (int c = 0; c < 32; c++) cnt += (key[c] >= cand) ? 1 : 0;
            for (int o = 32; o; o >>= 1) cnt += __shfl_xor(cnt, o);
            if (cnt >= KK) P = cand;
        }
        float z = 0.f;
#pragma unroll
        for (int c = 0; c < 32; c++) {
            float e = (key[c] >= P) ? __expf(s[c] - m) : 0.f;
            z += e;
            sc[row][c * 64 + lane] = e;
        }
        for (int o = 32; o; o >>= 1) z += __shfl_xor(z, o);
        if (lane == 0) zs[row] = z;
    }
    __syncthreads();

    // PV: thread (g = tid>>6, d = tid&63) does rows g*4..g*4+3, dim d
    int d = tid & 63, g = tid >> 6;
    const float* vcol = base + 2048 + h * 64 + d;
    float acc[4];
#pragma unroll
    for (int rr = 0; rr < 4; rr++) acc[rr] = 0.f;
    for (int j = 0; j < 2048; j++) {
        float v = vcol[(size_t)j * 4096];
#pragma unroll
        for (int rr = 0; rr < 4; rr++) acc[rr] += sc[g * 4 + rr][j] * v;
    }
#pragma unroll
    for (int rr = 0; rr < 4; rr++) {
        int row = g * 4 + rr;
        ao[(size_t)(b * SS + qt * 16 + row) * 1024 + h * 64 + d] = acc[rr] / zs[row];
    }
}

// ---------------------------------------------------------------------------
// 5) scalar output GEMM + highway: out = gate*(AO@Wo+bo) + (1-gate)*x
// ---------------------------------------------------------------------------
__global__ __launch_bounds__(256) void gemm_out_s(
        const float* AO, const float* Wo, const float* bo,
        const float* Qh, const float* x, float* out) {
    __shared__ float as[64][65];
    int tid = threadIdx.x;
    int n = blockIdx.x * 256 + tid;          // 0..1023
    int m0 = blockIdx.y * 64;
    float acc[64];
#pragma unroll
    for (int i = 0; i < 64; i++) acc[i] = 0.f;
    int r = tid >> 2, c0 = (tid & 3) * 16;
    for (int k0 = 0; k0 < 1024; k0 += 64) {
        __syncthreads();
#pragma unroll
        for (int u = 0; u < 16; u++)
            as[r][c0 + u] = AO[(size_t)(m0 + r) * 1024 + k0 + c0 + u];
        __syncthreads();
        for (int kk = 0; kk < 64; kk++) {
            float w = Wo[(size_t)(k0 + kk) * 1024 + n];
#pragma unroll
            for (int mm = 0; mm < 64; mm++) acc[mm] += as[mm][kk] * w;
        }
    }
    float bias = bo[n];
    for (int mm = 0; mm < 64; mm++) {
        int row = m0 + mm;
        float gpre = Qh[(size_t)row * 4096 + 3072 + n];
        float gate = 1.f / (1.f + __expf(-gpre));
        float xv = x[(size_t)row * 1024 + n];
        float o = acc[mm] + bias;
        out[(size_t)row * 1024 + n] = gate * o + (1.f - gate) * xv;
    }
}

// ---------------------------------------------------------------------------
extern "C" void kernel_launch(void* const* d_in, const int* in_sizes, int n_in,
                              void* d_out, int out_size, void* d_ws, size_t ws_size,
                              hipStream_t stream) {
    const float* x  = (const float*)d_in[0];
    const float* Wq = (const float*)d_in[1];
    const float* bq = (const float*)d_in[2];
    const float* Wk = (const float*)d_in[3];
    const float* bk = (const float*)d_in[4];
    const float* Wv = (const float*)d_in[5];
    const float* bv = (const float*)d_in[6];
    const float* Wo = (const float*)d_in[7];
    const float* bo = (const float*)d_in[8];
    const float* Wt = (const float*)d_in[9];
    const float* bt = (const float*)d_in[10];
    const float* Wg = (const float*)d_in[11];
    const float* bg = (const float*)d_in[12];

    char* w = (char*)d_ws;
    float* accbuf = (float*)(w + OFF_SCAL);
    float* itemp  = accbuf + 2;
    float* Qh     = (float*)(w + OFF_QH);
    float* ao     = (float*)(w + OFF_AO);

    hipMemsetAsync(accbuf, 0, 2 * sizeof(float), stream);

    temp_partial<<<64, 256, 0, stream>>>(x, Wt, accbuf);
    temp_final<<<1, 64, 0, stream>>>(accbuf, bt, itemp);
    gemm_qkvg_s<<<dim3(16, 64), 256, 0, stream>>>(x, Wq, Wk, Wv, Wg, bq, bk, bv, bg, Qh);
    norm_qk<<<16384, 256, 0, stream>>>(Qh);
    attn16<<<4096, 256, 0, stream>>>(Qh, itemp, ao);
    gemm_out_s<<<dim3(4, 64), 256, 0, stream>>>(ao, Wo, bo, Qh, x, (float*)d_out);
}

// Round 6
// 1754.086 us; speedup vs baseline: 3.0573x; 3.0573x over previous
//
#include <hip/hip_runtime.h>

typedef unsigned short u16;
typedef __attribute__((ext_vector_type(4))) float f32x4;
typedef __attribute__((ext_vector_type(8))) short bf16x8;
typedef __attribute__((ext_vector_type(4))) int i32x4;

#define BB 2
#define SS 2048
#define DD 1024
#define HH 16
#define DH 64
#define KK 512

// workspace layout (bytes) — total ~77.2 MB (<= 80.1 MB proven safe in R5)
#define OFF_SCAL  ((size_t)0)                       // accbuf[2] f32, itemp[2] f32
#define OFF_WT    ((size_t)256)                     // 5 x 1024x1024 bf16 [n][k] = 10 MB
#define OFF_XB    (OFF_WT + (size_t)5*1024*1024*2)  // x bf16 [4096][1024] = 8 MB (aliases AO)
#define OFF_AO    OFF_XB                            // attn out bf16 [4096][1024] = 8 MB
#define OFF_QH    (OFF_XB + (size_t)4096*1024*2)    // Qh bf16 [4096][4096] = 32 MB
#define OFF_QN    (OFF_QH + (size_t)4096*4096*2)    // qn bf16 [B,H,S,64] = 8 MB
#define OFF_KN    (OFF_QN + (size_t)4096*1024*2)    // kn bf16 [B,H,S,64] = 8 MB
#define OFF_VT    (OFF_KN + (size_t)4096*1024*2)    // vt bf16 [B,H,64,S] = 8 MB

__device__ __forceinline__ float b2f(u16 u) { return __uint_as_float(((unsigned)u) << 16); }
__device__ __forceinline__ u16 f2b(float f) {
    unsigned u = __float_as_uint(f);
    return (u16)((u + 0x7fffu + ((u >> 16) & 1u)) >> 16);   // RNE
}
__device__ __forceinline__ unsigned fkey(float f) {
    unsigned u = __float_as_uint(f);
    return (u & 0x80000000u) ? ~u : (u | 0x80000000u);
}

// ---------------------------------------------------------------------------
// 0) convert x fp32 -> bf16
// ---------------------------------------------------------------------------
__global__ __launch_bounds__(256) void convert_x(const float* x, u16* xb) {
    int i = (blockIdx.x * 256 + threadIdx.x) * 4;
    float4 v = *(const float4*)(x + i);
    u16 r0 = f2b(v.x), r1 = f2b(v.y), r2 = f2b(v.z), r3 = f2b(v.w);
    xb[i] = r0; xb[i + 1] = r1; xb[i + 2] = r2; xb[i + 3] = r3;
}

// ---------------------------------------------------------------------------
// 1) transpose+convert the five 1024x1024 fp32 weights into WT bf16 [n][k]
// ---------------------------------------------------------------------------
__global__ __launch_bounds__(256) void transpose_w(
        const float* Wq, const float* Wk, const float* Wv, const float* Wg, const float* Wo,
        u16* WT) {
    int z = blockIdx.z;
    const float* src = (z == 0) ? Wq : (z == 1) ? Wk : (z == 2) ? Wv : (z == 3) ? Wg : Wo;
    u16* dst = WT + (size_t)z * 1024 * 1024;
    __shared__ float tile[64][65];
    int n0 = blockIdx.x * 64, k0 = blockIdx.y * 64;
    int rbase = threadIdx.x >> 6, c = threadIdx.x & 63;
#pragma unroll
    for (int i = 0; i < 16; i++) {
        int r = i * 4 + rbase;
        tile[r][c] = src[(size_t)(k0 + r) * 1024 + n0 + c];
    }
    __syncthreads();
#pragma unroll
    for (int i = 0; i < 16; i++) {
        int r = i * 4 + rbase;
        dst[(size_t)(n0 + r) * 1024 + k0 + c] = f2b(tile[c][r]);
    }
}

// ---------------------------------------------------------------------------
// 2) adaptive temperature (fp32, validated in R5)
// ---------------------------------------------------------------------------
__global__ __launch_bounds__(256) void temp_partial(const float* x, const float* Wt,
                                                    float* accbuf) {
    int b = blockIdx.x >> 5, ch = blockIdx.x & 31;
    float a = 0.f;
    for (int si = 0; si < 64; si++) {
        int s = ch * 64 + si;
        const float* xr = x + ((size_t)(b * SS + s)) * DD;
#pragma unroll
        for (int k = 0; k < 4; k++) {
            int c = threadIdx.x + k * 256;
            a += xr[c] * Wt[c];
        }
    }
    for (int o = 32; o; o >>= 1) a += __shfl_xor(a, o);
    __shared__ float red[4];
    if ((threadIdx.x & 63) == 0) red[threadIdx.x >> 6] = a;
    __syncthreads();
    if (threadIdx.x == 0) atomicAdd(&accbuf[b], red[0] + red[1] + red[2] + red[3]);
}

__global__ void temp_final(const float* accbuf, const float* bt, float* itemp) {
    int t = threadIdx.x;
    if (t < BB) {
        float v = accbuf[t] / (float)SS + bt[0];
        float tmp = 1.f / (1.f + __expf(-v)) + 0.5f;
        itemp[t] = 1.f / tmp;
    }
}

// ---------------------------------------------------------------------------
// 3) QKVG GEMM (MFMA): xb[4096,1024] x WT(4 mats) -> Qh bf16 [4096,4096] +bias
// ---------------------------------------------------------------------------
__global__ __launch_bounds__(256) void gemm_qkvg(
        const u16* X, const u16* WT,
        const float* bq, const float* bk, const float* bv, const float* bg, u16* Qh) {
    __shared__ u16 la[64 * 40];
    __shared__ u16 lb[64 * 40];
    int tid = threadIdx.x, wid = tid >> 6, lane = tid & 63;
    int m0 = blockIdx.x * 64, n0 = blockIdx.y * 64;
    int quad = lane >> 4, ml = lane & 15;
    f32x4 acc[4];
#pragma unroll
    for (int i = 0; i < 4; i++) acc[i] = (f32x4){0.f, 0.f, 0.f, 0.f};

    int sr = tid >> 2, sg = tid & 3;
    for (int k0 = 0; k0 < 1024; k0 += 32) {
        __syncthreads();
        *(i32x4*)&la[sr * 40 + sg * 8] = *(const i32x4*)&X[(size_t)(m0 + sr) * 1024 + k0 + sg * 8];
        *(i32x4*)&lb[sr * 40 + sg * 8] = *(const i32x4*)&WT[(size_t)(n0 + sr) * 1024 + k0 + sg * 8];
        __syncthreads();
        bf16x8 a = *(const bf16x8*)&la[(wid * 16 + ml) * 40 + quad * 8];
#pragma unroll
        for (int nt = 0; nt < 4; nt++) {
            bf16x8 bfr = *(const bf16x8*)&lb[(nt * 16 + ml) * 40 + quad * 8];
            acc[nt] = __builtin_amdgcn_mfma_f32_16x16x32_bf16(a, bfr, acc[nt], 0, 0, 0);
        }
    }
#pragma unroll
    for (int nt = 0; nt < 4; nt++) {
        int col = n0 + nt * 16 + ml;
        int mat = col >> 10, bc = col & 1023;
        const float* bp = (mat == 0) ? bq : (mat == 1) ? bk : (mat == 2) ? bv : bg;
        float bias = bp[bc];
#pragma unroll
        for (int r = 0; r < 4; r++) {
            int row = m0 + wid * 16 + quad * 4 + r;
            Qh[(size_t)row * 4096 + col] = f2b(acc[nt][r] + bias);
        }
    }
}

// ---------------------------------------------------------------------------
// 4) normalize q,k -> packed qn,kn [B,H,S,64]; repack v -> vt [B,H,64,S]
// ---------------------------------------------------------------------------
__global__ __launch_bounds__(256) void norm_repack(const u16* Qh, u16* qn, u16* kn, u16* vt) {
    int wid = threadIdx.x >> 6, lane = threadIdx.x & 63;
    int idx = blockIdx.x * 4 + wid;          // (token, head), 65536 total
    int token = idx >> 4, h = idx & 15;
    int b = token >> 11, s = token & 2047;
    int bh = b * HH + h;
    const u16* rowp = Qh + (size_t)token * 4096 + h * 64;
    float q = b2f(rowp[lane]);
    float k = b2f(rowp[1024 + lane]);
    u16 v = rowp[2048 + lane];
    float sq = q * q, sk = k * k;
    for (int o = 32; o; o >>= 1) { sq += __shfl_xor(sq, o); sk += __shfl_xor(sk, o); }
    float qd = fmaxf(sqrtf(sq), 1e-12f), kd = fmaxf(sqrtf(sk), 1e-12f);
    qn[((size_t)bh * SS + s) * DH + lane] = f2b(q / qd);
    kn[((size_t)bh * SS + s) * DH + lane] = f2b(k / kd);
    vt[((size_t)bh * DH + lane) * SS + s] = v;
}

// ---------------------------------------------------------------------------
// 5) attention: block = (b,h,16 q rows). MFMA scores -> LDS fp32; per-wave
//    in-register exact top-512 threshold (R5-validated algorithm); exp; MFMA PV.
// ---------------------------------------------------------------------------
#define SCP 2052

__global__ __launch_bounds__(256) void attn_kernel(
        const u16* qn, const u16* kn, const u16* vt, const float* itemp, u16* ao) {
    __shared__ float sc[16 * SCP];          // 131328 B
    __shared__ u16 stage[64 * 72];          // 9216 B
    __shared__ float zrow_s[16];

    int tid = threadIdx.x, wid = tid >> 6, lane = tid & 63;
    int quad = lane >> 4, nl = lane & 15;
    int bh = blockIdx.x >> 7, qt = blockIdx.x & 127;
    int b = bh >> 4, h = bh & 15;
    const u16* qbase = qn + ((size_t)bh * SS + qt * 16) * DH;
    const u16* kbase = kn + (size_t)bh * SS * DH;
    const u16* vbase = vt + (size_t)bh * DH * SS;
    float it = itemp[b];

    // q A-fragments: lane holds q[m=nl][k=quad*8+j (+32)]
    bf16x8 aq0 = *(const bf16x8*)(qbase + nl * DH + quad * 8);
    bf16x8 aq1 = *(const bf16x8*)(qbase + nl * DH + 32 + quad * 8);

    // ---- scores: 32 chunks of 64 keys ----
    int sr = tid >> 3, sg8 = tid & 7;
    for (int c = 0; c < 32; c++) {
        int j0 = c * 64;
        __syncthreads();
#pragma unroll
        for (int i = 0; i < 64; i += 32)
            *(i32x4*)&stage[(sr + i) * 72 + sg8 * 8] =
                *(const i32x4*)&kbase[(size_t)(j0 + sr + i) * DH + sg8 * 8];
        __syncthreads();
        f32x4 acc = (f32x4){0.f, 0.f, 0.f, 0.f};
        const u16* bp = &stage[(wid * 16 + nl) * 72 + quad * 8];
        bf16x8 b0 = *(const bf16x8*)bp;
        bf16x8 b1 = *(const bf16x8*)(bp + 32);
        acc = __builtin_amdgcn_mfma_f32_16x16x32_bf16(aq0, b0, acc, 0, 0, 0);
        acc = __builtin_amdgcn_mfma_f32_16x16x32_bf16(aq1, b1, acc, 0, 0, 0);
        int colg = j0 + wid * 16 + nl;
#pragma unroll
        for (int r = 0; r < 4; r++) sc[(quad * 4 + r) * SCP + colg] = acc[r] * it;
    }
    __syncthreads();

    // ---- per-wave exact top-512 threshold + exp + Z (R5-validated) ----
    for (int rr = 0; rr < 4; rr++) {
        int row = wid * 4 + rr;
        float s[32];
        unsigned key[32];
#pragma unroll
        for (int c = 0; c < 32; c++) {
            s[c] = sc[row * SCP + c * 64 + lane];
            key[c] = fkey(s[c]);
        }
        float m = s[0];
#pragma unroll
        for (int c = 1; c < 32; c++) m = fmaxf(m, s[c]);
        for (int o = 32; o; o >>= 1) m = fmaxf(m, __shfl_xor(m, o));
        unsigned P = 0u;
        for (int bit = 31; bit >= 0; bit--) {
            unsigned cand = P | (1u << bit);
            int cnt = 0;
#pragma unroll
            for (int c = 0; c < 32; c++) cnt += (key[c] >= cand) ? 1 : 0;
            for (int o = 32; o; o >>= 1) cnt += __shfl_xor(cnt, o);
            if (cnt >= KK) P = cand;
        }
        float z = 0.f;
#pragma unroll
        for (int c = 0; c < 32; c++) {
            float e = (key[c] >= P) ? __expf(s[c] - m) : 0.f;
            z += e;
            sc[row * SCP + c * 64 + lane] = e;
        }
        for (int o = 32; o; o >>= 1) z += __shfl_xor(z, o);
        if (lane == 0) zrow_s[row] = z;
    }

    // ---- PV: out[16q][64dh] = E[16,2048] x V[2048,64] via MFMA ----
    f32x4 accp = (f32x4){0.f, 0.f, 0.f, 0.f};
    for (int c = 0; c < 32; c++) {
        int j0 = c * 64;
        __syncthreads();
#pragma unroll
        for (int i = 0; i < 64; i += 32)
            *(i32x4*)&stage[(sr + i) * 72 + sg8 * 8] =
                *(const i32x4*)&vbase[(size_t)(sr + i) * SS + j0 + sg8 * 8];
        __syncthreads();
#pragma unroll
        for (int ks = 0; ks < 2; ks++) {
            const float* ep = &sc[nl * SCP + j0 + ks * 32 + quad * 8];
            f32x4 e0 = *(const f32x4*)ep;
            f32x4 e1 = *(const f32x4*)(ep + 4);
            union { bf16x8 v; u16 hx[8]; } au;
#pragma unroll
            for (int i = 0; i < 4; i++) { au.hx[i] = f2b(e0[i]); au.hx[4 + i] = f2b(e1[i]); }
            bf16x8 bfr = *(const bf16x8*)&stage[(wid * 16 + nl) * 72 + ks * 32 + quad * 8];
            accp = __builtin_amdgcn_mfma_f32_16x16x32_bf16(au.v, bfr, accp, 0, 0, 0);
        }
    }
    __syncthreads();

    // ---- epilogue: scale by 1/Z, write ao bf16 [B,S,H,dh] ----
    {
        int dh = wid * 16 + nl;
#pragma unroll
        for (int r = 0; r < 4; r++) {
            int q = quad * 4 + r;
            float val = accp[r] / zrow_s[q];
            size_t row = (size_t)(b * SS + qt * 16 + q);
            ao[row * DD + h * 64 + dh] = f2b(val);
        }
    }
}

// ---------------------------------------------------------------------------
// 6) out = attn_out @ Wo + bo, highway: gate*out + (1-gate)*x -> fp32
// ---------------------------------------------------------------------------
__global__ __launch_bounds__(256) void gemm_out(
        const u16* AO, const u16* WTo, const float* bo,
        const u16* Qh, const float* x, float* out) {
    __shared__ u16 la[64 * 40];
    __shared__ u16 lb[64 * 40];
    int tid = threadIdx.x, wid = tid >> 6, lane = tid & 63;
    int m0 = blockIdx.x * 64, n0 = blockIdx.y * 64;
    int quad = lane >> 4, ml = lane & 15;
    f32x4 acc[4];
#pragma unroll
    for (int i = 0; i < 4; i++) acc[i] = (f32x4){0.f, 0.f, 0.f, 0.f};

    int sr = tid >> 2, sg = tid & 3;
    for (int k0 = 0; k0 < 1024; k0 += 32) {
        __syncthreads();
        *(i32x4*)&la[sr * 40 + sg * 8] = *(const i32x4*)&AO[(size_t)(m0 + sr) * 1024 + k0 + sg * 8];
        *(i32x4*)&lb[sr * 40 + sg * 8] = *(const i32x4*)&WTo[(size_t)(n0 + sr) * 1024 + k0 + sg * 8];
        __syncthreads();
        bf16x8 a = *(const bf16x8*)&la[(wid * 16 + ml) * 40 + quad * 8];
#pragma unroll
        for (int nt = 0; nt < 4; nt++) {
            bf16x8 bfr = *(const bf16x8*)&lb[(nt * 16 + ml) * 40 + quad * 8];
            acc[nt] = __builtin_amdgcn_mfma_f32_16x16x32_bf16(a, bfr, acc[nt], 0, 0, 0);
        }
    }
#pragma unroll
    for (int nt = 0; nt < 4; nt++) {
        int col = n0 + nt * 16 + ml;
        float bias = bo[col];
#pragma unroll
        for (int r = 0; r < 4; r++) {
            int row = m0 + wid * 16 + quad * 4 + r;
            float g = b2f(Qh[(size_t)row * 4096 + 3072 + col]);
            float gate = 1.f / (1.f + __expf(-g));
            float xv = x[(size_t)row * 1024 + col];
            float o = acc[nt][r] + bias;
            out[(size_t)row * 1024 + col] = gate * o + (1.f - gate) * xv;
        }
    }
}

// ---------------------------------------------------------------------------
extern "C" void kernel_launch(void* const* d_in, const int* in_sizes, int n_in,
                              void* d_out, int out_size, void* d_ws, size_t ws_size,
                              hipStream_t stream) {
    const float* x  = (const float*)d_in[0];
    const float* Wq = (const float*)d_in[1];
    const float* bq = (const float*)d_in[2];
    const float* Wk = (const float*)d_in[3];
    const float* bk = (const float*)d_in[4];
    const float* Wv = (const float*)d_in[5];
    const float* bv = (const float*)d_in[6];
    const float* Wo = (const float*)d_in[7];
    const float* bo = (const float*)d_in[8];
    const float* Wt = (const float*)d_in[9];
    const float* bt = (const float*)d_in[10];
    const float* Wg = (const float*)d_in[11];
    const float* bg = (const float*)d_in[12];

    char* w = (char*)d_ws;
    float* accbuf = (float*)(w + OFF_SCAL);
    float* itemp  = accbuf + 2;
    u16*   WT     = (u16*)(w + OFF_WT);
    u16*   xb     = (u16*)(w + OFF_XB);
    u16*   ao     = (u16*)(w + OFF_AO);   // aliases xb (disjoint lifetime)
    u16*   Qh     = (u16*)(w + OFF_QH);
    u16*   qn     = (u16*)(w + OFF_QN);
    u16*   kn     = (u16*)(w + OFF_KN);
    u16*   vt     = (u16*)(w + OFF_VT);

    hipMemsetAsync(accbuf, 0, 2 * sizeof(float), stream);

    convert_x<<<4096, 256, 0, stream>>>(x, xb);
    transpose_w<<<dim3(16, 16, 5), 256, 0, stream>>>(Wq, Wk, Wv, Wg, Wo, WT);
    temp_partial<<<64, 256, 0, stream>>>(x, Wt, accbuf);
    temp_final<<<1, 64, 0, stream>>>(accbuf, bt, itemp);
    gemm_qkvg<<<dim3(64, 64), 256, 0, stream>>>(xb, WT, bq, bk, bv, bg, Qh);
    norm_repack<<<16384, 256, 0, stream>>>(Qh, qn, kn, vt);
    attn_kernel<<<4096, 256, 0, stream>>>(qn, kn, vt, itemp, ao);
    gemm_out<<<dim3(64, 16), 256, 0, stream>>>(ao, WT + (size_t)4 * 1024 * 1024, bo, Qh, x,
                                               (float*)d_out);
}

// Round 7
// 717.290 us; speedup vs baseline: 7.4763x; 2.4454x over previous
//
#include <hip/hip_runtime.h>

typedef unsigned short u16;
typedef __attribute__((ext_vector_type(4))) float f32x4;
typedef __attribute__((ext_vector_type(8))) short bf16x8;
typedef __attribute__((ext_vector_type(4))) int i32x4;

#define BB 2
#define SS 2048
#define DD 1024
#define HH 16
#define DH 64
#define KK 512

// workspace layout (bytes) — total ~77.2 MB (<= 80.1 MB proven safe in R5)
#define OFF_SCAL  ((size_t)0)                       // accbuf[2] f32, itemp[2] f32
#define OFF_WT    ((size_t)256)                     // 5 x 1024x1024 bf16 [n][k] = 10 MB
#define OFF_XB    (OFF_WT + (size_t)5*1024*1024*2)  // x bf16 [4096][1024] = 8 MB (aliases AO)
#define OFF_AO    OFF_XB                            // attn out bf16 [4096][1024] = 8 MB
#define OFF_QH    (OFF_XB + (size_t)4096*1024*2)    // Qh bf16 [4096][4096] = 32 MB
#define OFF_QN    (OFF_QH + (size_t)4096*4096*2)    // qn bf16 [B,H,S,64] = 8 MB
#define OFF_KN    (OFF_QN + (size_t)4096*1024*2)    // kn bf16 [B,H,S,64] = 8 MB
#define OFF_VT    (OFF_KN + (size_t)4096*1024*2)    // vt bf16 [B,H,64,S] = 8 MB

__device__ __forceinline__ float b2f(u16 u) { return __uint_as_float(((unsigned)u) << 16); }
__device__ __forceinline__ u16 f2b(float f) {
    unsigned u = __float_as_uint(f);
    return (u16)((u + 0x7fffu + ((u >> 16) & 1u)) >> 16);   // RNE
}

// ---------------------------------------------------------------------------
// 0) convert x fp32 -> bf16
// ---------------------------------------------------------------------------
__global__ __launch_bounds__(256) void convert_x(const float* x, u16* xb) {
    int i = (blockIdx.x * 256 + threadIdx.x) * 4;
    float4 v = *(const float4*)(x + i);
    u16 r0 = f2b(v.x), r1 = f2b(v.y), r2 = f2b(v.z), r3 = f2b(v.w);
    xb[i] = r0; xb[i + 1] = r1; xb[i + 2] = r2; xb[i + 3] = r3;
}

// ---------------------------------------------------------------------------
// 1) transpose+convert the five 1024x1024 fp32 weights into WT bf16 [n][k]
// ---------------------------------------------------------------------------
__global__ __launch_bounds__(256) void transpose_w(
        const float* Wq, const float* Wk, const float* Wv, const float* Wg, const float* Wo,
        u16* WT) {
    int z = blockIdx.z;
    const float* src = (z == 0) ? Wq : (z == 1) ? Wk : (z == 2) ? Wv : (z == 3) ? Wg : Wo;
    u16* dst = WT + (size_t)z * 1024 * 1024;
    __shared__ float tile[64][65];
    int n0 = blockIdx.x * 64, k0 = blockIdx.y * 64;
    int rbase = threadIdx.x >> 6, c = threadIdx.x & 63;
#pragma unroll
    for (int i = 0; i < 16; i++) {
        int r = i * 4 + rbase;
        tile[r][c] = src[(size_t)(k0 + r) * 1024 + n0 + c];
    }
    __syncthreads();
#pragma unroll
    for (int i = 0; i < 16; i++) {
        int r = i * 4 + rbase;
        dst[(size_t)(n0 + r) * 1024 + k0 + c] = f2b(tile[c][r]);
    }
}

// ---------------------------------------------------------------------------
// 2) adaptive temperature (fp32, validated in R5)
// ---------------------------------------------------------------------------
__global__ __launch_bounds__(256) void temp_partial(const float* x, const float* Wt,
                                                    float* accbuf) {
    int b = blockIdx.x >> 5, ch = blockIdx.x & 31;
    float a = 0.f;
    for (int si = 0; si < 64; si++) {
        int s = ch * 64 + si;
        const float* xr = x + ((size_t)(b * SS + s)) * DD;
#pragma unroll
        for (int k = 0; k < 4; k++) {
            int c = threadIdx.x + k * 256;
            a += xr[c] * Wt[c];
        }
    }
    for (int o = 32; o; o >>= 1) a += __shfl_xor(a, o);
    __shared__ float red[4];
    if ((threadIdx.x & 63) == 0) red[threadIdx.x >> 6] = a;
    __syncthreads();
    if (threadIdx.x == 0) atomicAdd(&accbuf[b], red[0] + red[1] + red[2] + red[3]);
}

__global__ void temp_final(const float* accbuf, const float* bt, float* itemp) {
    int t = threadIdx.x;
    if (t < BB) {
        float v = accbuf[t] / (float)SS + bt[0];
        float tmp = 1.f / (1.f + __expf(-v)) + 0.5f;
        itemp[t] = 1.f / tmp;
    }
}

// ---------------------------------------------------------------------------
// 3) QKVG GEMM (MFMA): xb[4096,1024] x WT(4 mats) -> Qh bf16 [4096,4096] +bias
// ---------------------------------------------------------------------------
__global__ __launch_bounds__(256) void gemm_qkvg(
        const u16* X, const u16* WT,
        const float* bq, const float* bk, const float* bv, const float* bg, u16* Qh) {
    __shared__ u16 la[64 * 40];
    __shared__ u16 lb[64 * 40];
    int tid = threadIdx.x, wid = tid >> 6, lane = tid & 63;
    int m0 = blockIdx.x * 64, n0 = blockIdx.y * 64;
    int quad = lane >> 4, ml = lane & 15;
    f32x4 acc[4];
#pragma unroll
    for (int i = 0; i < 4; i++) acc[i] = (f32x4){0.f, 0.f, 0.f, 0.f};

    int sr = tid >> 2, sg = tid & 3;
    for (int k0 = 0; k0 < 1024; k0 += 32) {
        __syncthreads();
        *(i32x4*)&la[sr * 40 + sg * 8] = *(const i32x4*)&X[(size_t)(m0 + sr) * 1024 + k0 + sg * 8];
        *(i32x4*)&lb[sr * 40 + sg * 8] = *(const i32x4*)&WT[(size_t)(n0 + sr) * 1024 + k0 + sg * 8];
        __syncthreads();
        bf16x8 a = *(const bf16x8*)&la[(wid * 16 + ml) * 40 + quad * 8];
#pragma unroll
        for (int nt = 0; nt < 4; nt++) {
            bf16x8 bfr = *(const bf16x8*)&lb[(nt * 16 + ml) * 40 + quad * 8];
            acc[nt] = __builtin_amdgcn_mfma_f32_16x16x32_bf16(a, bfr, acc[nt], 0, 0, 0);
        }
    }
#pragma unroll
    for (int nt = 0; nt < 4; nt++) {
        int col = n0 + nt * 16 + ml;
        int mat = col >> 10, bc = col & 1023;
        const float* bp = (mat == 0) ? bq : (mat == 1) ? bk : (mat == 2) ? bv : bg;
        float bias = bp[bc];
#pragma unroll
        for (int r = 0; r < 4; r++) {
            int row = m0 + wid * 16 + quad * 4 + r;
            Qh[(size_t)row * 4096 + col] = f2b(acc[nt][r] + bias);
        }
    }
}

// ---------------------------------------------------------------------------
// 4) normalize q,k -> packed qn,kn [B,H,S,64]; repack v -> vt [B,H,64,S]
// ---------------------------------------------------------------------------
__global__ __launch_bounds__(256) void norm_repack(const u16* Qh, u16* qn, u16* kn, u16* vt) {
    int wid = threadIdx.x >> 6, lane = threadIdx.x & 63;
    int idx = blockIdx.x * 4 + wid;          // (token, head), 65536 total
    int token = idx >> 4, h = idx & 15;
    int b = token >> 11, s = token & 2047;
    int bh = b * HH + h;
    const u16* rowp = Qh + (size_t)token * 4096 + h * 64;
    float q = b2f(rowp[lane]);
    float k = b2f(rowp[1024 + lane]);
    u16 v = rowp[2048 + lane];
    float sq = q * q, sk = k * k;
    for (int o = 32; o; o >>= 1) { sq += __shfl_xor(sq, o); sk += __shfl_xor(sk, o); }
    float qd = fmaxf(sqrtf(sq), 1e-12f), kd = fmaxf(sqrtf(sk), 1e-12f);
    qn[((size_t)bh * SS + s) * DH + lane] = f2b(q / qd);
    kn[((size_t)bh * SS + s) * DH + lane] = f2b(k / kd);
    vt[((size_t)bh * DH + lane) * SS + s] = v;
}

// ---------------------------------------------------------------------------
// 5) attention: block = (b,h,16 q rows). No LDS staging: MFMA B-fragments are
//    loaded b128 straight from global (kn row-major, vt S-major). Scores live
//    bf16 in LDS (66.8 KB -> 2 blocks/CU). 16-bit key bit-search select.
// ---------------------------------------------------------------------------
#define EST 2088   // u16 stride: (EST/2)%32==20 -> b128 A-frag reads spread all 32 banks

__global__ __launch_bounds__(256, 2) void attn_kernel(
        const u16* qn, const u16* kn, const u16* vt, const float* itemp, u16* ao) {
    __shared__ __align__(16) u16 e16[16 * EST];   // 66816 B
    __shared__ float zrow_s[16];

    int tid = threadIdx.x, wid = tid >> 6, lane = tid & 63;
    int quad = lane >> 4, nl = lane & 15;
    int bh = blockIdx.x >> 7, qt = blockIdx.x & 127;
    int b = bh >> 4, h = bh & 15;
    const u16* qbase = qn + ((size_t)bh * SS + qt * 16) * DH;
    const u16* kbase = kn + (size_t)bh * SS * DH;
    const u16* vbase = vt + (size_t)bh * DH * SS;
    float it = itemp[b];

    // q A-fragments: lane holds q[m=nl][k=quad*8+j (+32)]
    bf16x8 aq0 = *(const bf16x8*)(qbase + nl * DH + quad * 8);
    bf16x8 aq1 = *(const bf16x8*)(qbase + nl * DH + 32 + quad * 8);

    // ---- scores: barrier-free; wave wid covers cols wid*16+nl (mod 64) ----
#pragma unroll 4
    for (int c = 0; c < 32; c++) {
        int j = c * 64 + wid * 16 + nl;
        const u16* kr = kbase + (size_t)j * DH;
        bf16x8 b0 = *(const bf16x8*)(kr + quad * 8);
        bf16x8 b1 = *(const bf16x8*)(kr + 32 + quad * 8);
        f32x4 acc = (f32x4){0.f, 0.f, 0.f, 0.f};
        acc = __builtin_amdgcn_mfma_f32_16x16x32_bf16(aq0, b0, acc, 0, 0, 0);
        acc = __builtin_amdgcn_mfma_f32_16x16x32_bf16(aq1, b1, acc, 0, 0, 0);
#pragma unroll
        for (int r = 0; r < 4; r++) e16[(quad * 4 + r) * EST + j] = f2b(acc[r] * it);
    }
    __syncthreads();

    // ---- per-wave: 16-bit-key exact threshold + exp + Z (4 rows/wave) ----
    for (int rr = 0; rr < 4; rr++) {
        int row = wid * 4 + rr;
        float s[32];
        int key[32];
#pragma unroll
        for (int c = 0; c < 32; c++) {
            u16 raw = e16[row * EST + c * 64 + lane];
            key[c] = (raw & 0x8000) ? (int)(raw ^ 0xFFFFu) : (int)(raw | 0x8000u);
            s[c] = b2f(raw);
        }
        float m = s[0];
#pragma unroll
        for (int c = 1; c < 32; c++) m = fmaxf(m, s[c]);
        for (int o = 32; o; o >>= 1) m = fmaxf(m, __shfl_xor(m, o));
        int P = 0;
        for (int bit = 15; bit >= 0; bit--) {
            int cand = P | (1 << bit);
            int cnt = 0;
#pragma unroll
            for (int c = 0; c < 32; c++) cnt += (key[c] >= cand) ? 1 : 0;
            for (int o = 32; o; o >>= 1) cnt += __shfl_xor(cnt, o);
            if (cnt >= KK) P = cand;
        }
        float z = 0.f;
#pragma unroll
        for (int c = 0; c < 32; c++) {
            float e = (key[c] >= P) ? __expf(s[c] - m) : 0.f;
            z += e;
            e16[row * EST + c * 64 + lane] = f2b(e);
        }
        for (int o = 32; o; o >>= 1) z += __shfl_xor(z, o);
        if (lane == 0) zrow_s[row] = z;
    }
    __syncthreads();

    // ---- PV: out[16q][64dh] = E[16,2048] x V[2048,64]; barrier-free ----
    f32x4 accp = (f32x4){0.f, 0.f, 0.f, 0.f};
    const u16* vrow = vbase + (size_t)(wid * 16 + nl) * SS;   // dh = wid*16+nl
#pragma unroll 4
    for (int c = 0; c < 32; c++) {
        int j0 = c * 64;
#pragma unroll
        for (int ks = 0; ks < 2; ks++) {
            bf16x8 a = *(const bf16x8*)&e16[nl * EST + j0 + ks * 32 + quad * 8];
            bf16x8 bfr = *(const bf16x8*)(vrow + j0 + ks * 32 + quad * 8);
            accp = __builtin_amdgcn_mfma_f32_16x16x32_bf16(a, bfr, accp, 0, 0, 0);
        }
    }

    // ---- epilogue: scale by 1/Z, write ao bf16 [B,S,H,dh] ----
    {
        int dh = wid * 16 + nl;
#pragma unroll
        for (int r = 0; r < 4; r++) {
            int q = quad * 4 + r;
            float val = accp[r] / zrow_s[q];
            size_t row = (size_t)(b * SS + qt * 16 + q);
            ao[row * DD + h * 64 + dh] = f2b(val);
        }
    }
}

// ---------------------------------------------------------------------------
// 6) out = attn_out @ Wo + bo, highway: gate*out + (1-gate)*x -> fp32
// ---------------------------------------------------------------------------
__global__ __launch_bounds__(256) void gemm_out(
        const u16* AO, const u16* WTo, const float* bo,
        const u16* Qh, const float* x, float* out) {
    __shared__ u16 la[64 * 40];
    __shared__ u16 lb[64 * 40];
    int tid = threadIdx.x, wid = tid >> 6, lane = tid & 63;
    int m0 = blockIdx.x * 64, n0 = blockIdx.y * 64;
    int quad = lane >> 4, ml = lane & 15;
    f32x4 acc[4];
#pragma unroll
    for (int i = 0; i < 4; i++) acc[i] = (f32x4){0.f, 0.f, 0.f, 0.f};

    int sr = tid >> 2, sg = tid & 3;
    for (int k0 = 0; k0 < 1024; k0 += 32) {
        __syncthreads();
        *(i32x4*)&la[sr * 40 + sg * 8] = *(const i32x4*)&AO[(size_t)(m0 + sr) * 1024 + k0 + sg * 8];
        *(i32x4*)&lb[sr * 40 + sg * 8] = *(const i32x4*)&WTo[(size_t)(n0 + sr) * 1024 + k0 + sg * 8];
        __syncthreads();
        bf16x8 a = *(const bf16x8*)&la[(wid * 16 + ml) * 40 + quad * 8];
#pragma unroll
        for (int nt = 0; nt < 4; nt++) {
            bf16x8 bfr = *(const bf16x8*)&lb[(nt * 16 + ml) * 40 + quad * 8];
            acc[nt] = __builtin_amdgcn_mfma_f32_16x16x32_bf16(a, bfr, acc[nt], 0, 0, 0);
        }
    }
#pragma unroll
    for (int nt = 0; nt < 4; nt++) {
        int col = n0 + nt * 16 + ml;
        float bias = bo[col];
#pragma unroll
        for (int r = 0; r < 4; r++) {
            int row = m0 + wid * 16 + quad * 4 + r;
            float g = b2f(Qh[(size_t)row * 4096 + 3072 + col]);
            float gate = 1.f / (1.f + __expf(-g));
            float xv = x[(size_t)row * 1024 + col];
            float o = acc[nt][r] + bias;
            out[(size_t)row * 1024 + col] = gate * o + (1.f - gate) * xv;
        }
    }
}

// ---------------------------------------------------------------------------
extern "C" void kernel_launch(void* const* d_in, const int* in_sizes, int n_in,
                              void* d_out, int out_size, void* d_ws, size_t ws_size,
                              hipStream_t stream) {
    const float* x  = (const float*)d_in[0];
    const float* Wq = (const float*)d_in[1];
    const float* bq = (const float*)d_in[2];
    const float* Wk = (const float*)d_in[3];
    const float* bk = (const float*)d_in[4];
    const float* Wv = (const float*)d_in[5];
    const float* bv = (const float*)d_in[6];
    const float* Wo = (const float*)d_in[7];
    const float* bo = (const float*)d_in[8];
    const float* Wt = (const float*)d_in[9];
    const float* bt = (const float*)d_in[10];
    const float* Wg = (const float*)d_in[11];
    const float* bg = (const float*)d_in[12];

    char* w = (char*)d_ws;
    float* accbuf = (float*)(w + OFF_SCAL);
    float* itemp  = accbuf + 2;
    u16*   WT     = (u16*)(w + OFF_WT);
    u16*   xb     = (u16*)(w + OFF_XB);
    u16*   ao     = (u16*)(w + OFF_AO);   // aliases xb (disjoint lifetime)
    u16*   Qh     = (u16*)(w + OFF_QH);
    u16*   qn     = (u16*)(w + OFF_QN);
    u16*   kn     = (u16*)(w + OFF_KN);
    u16*   vt     = (u16*)(w + OFF_VT);

    hipMemsetAsync(accbuf, 0, 2 * sizeof(float), stream);

    convert_x<<<4096, 256, 0, stream>>>(x, xb);
    transpose_w<<<dim3(16, 16, 5), 256, 0, stream>>>(Wq, Wk, Wv, Wg, Wo, WT);
    temp_partial<<<64, 256, 0, stream>>>(x, Wt, accbuf);
    temp_final<<<1, 64, 0, stream>>>(accbuf, bt, itemp);
    gemm_qkvg<<<dim3(64, 64), 256, 0, stream>>>(xb, WT, bq, bk, bv, bg, Qh);
    norm_repack<<<16384, 256, 0, stream>>>(Qh, qn, kn, vt);
    attn_kernel<<<4096, 256, 0, stream>>>(qn, kn, vt, itemp, ao);
    gemm_out<<<dim3(64, 16), 256, 0, stream>>>(ao, WT + (size_t)4 * 1024 * 1024, bo, Qh, x,
                                               (float*)d_out);
}

// Round 8
// 631.555 us; speedup vs baseline: 8.4912x; 1.1358x over previous
//
#include <hip/hip_runtime.h>

typedef unsigned short u16;
typedef __attribute__((ext_vector_type(4))) float f32x4;
typedef __attribute__((ext_vector_type(8))) short bf16x8;
typedef __attribute__((ext_vector_type(4))) int i32x4;

#define BB 2
#define SS 2048
#define DD 1024
#define HH 16
#define DH 64
#define KK 512

// workspace layout (bytes) — total ~77.2 MB (<= 80.1 MB proven safe in R5)
#define OFF_SCAL  ((size_t)0)                       // accbuf[2] f32, itemp[2] f32
#define OFF_WT    ((size_t)256)                     // 5 x 1024x1024 bf16 [n][k] = 10 MB
#define OFF_XB    (OFF_WT + (size_t)5*1024*1024*2)  // x bf16 [4096][1024] = 8 MB (aliases AO)
#define OFF_AO    OFF_XB                            // attn out bf16 [4096][1024] = 8 MB
#define OFF_QH    (OFF_XB + (size_t)4096*1024*2)    // Qh bf16 [4096][4096] = 32 MB
#define OFF_QN    (OFF_QH + (size_t)4096*4096*2)    // qn bf16 [B,H,S,64] = 8 MB
#define OFF_KN    (OFF_QN + (size_t)4096*1024*2)    // kn bf16 [B,H,S,64] = 8 MB
#define OFF_VT    (OFF_KN + (size_t)4096*1024*2)    // vt bf16 [B,H,64,S] = 8 MB

__device__ __forceinline__ float b2f(u16 u) { return __uint_as_float(((unsigned)u) << 16); }
__device__ __forceinline__ u16 f2b(float f) {
    unsigned u = __float_as_uint(f);
    return (u16)((u + 0x7fffu + ((u >> 16) & 1u)) >> 16);   // RNE
}

// ---------------------------------------------------------------------------
// 0) convert x fp32 -> bf16
// ---------------------------------------------------------------------------
__global__ __launch_bounds__(256) void convert_x(const float* x, u16* xb) {
    int i = (blockIdx.x * 256 + threadIdx.x) * 4;
    float4 v = *(const float4*)(x + i);
    u16 r0 = f2b(v.x), r1 = f2b(v.y), r2 = f2b(v.z), r3 = f2b(v.w);
    xb[i] = r0; xb[i + 1] = r1; xb[i + 2] = r2; xb[i + 3] = r3;
}

// ---------------------------------------------------------------------------
// 1) transpose+convert the five 1024x1024 fp32 weights into WT bf16 [n][k]
// ---------------------------------------------------------------------------
__global__ __launch_bounds__(256) void transpose_w(
        const float* Wq, const float* Wk, const float* Wv, const float* Wg, const float* Wo,
        u16* WT) {
    int z = blockIdx.z;
    const float* src = (z == 0) ? Wq : (z == 1) ? Wk : (z == 2) ? Wv : (z == 3) ? Wg : Wo;
    u16* dst = WT + (size_t)z * 1024 * 1024;
    __shared__ float tile[64][65];
    int n0 = blockIdx.x * 64, k0 = blockIdx.y * 64;
    int rbase = threadIdx.x >> 6, c = threadIdx.x & 63;
#pragma unroll
    for (int i = 0; i < 16; i++) {
        int r = i * 4 + rbase;
        tile[r][c] = src[(size_t)(k0 + r) * 1024 + n0 + c];
    }
    __syncthreads();
#pragma unroll
    for (int i = 0; i < 16; i++) {
        int r = i * 4 + rbase;
        dst[(size_t)(n0 + r) * 1024 + k0 + c] = f2b(tile[c][r]);
    }
}

// ---------------------------------------------------------------------------
// 2) adaptive temperature (fp32, validated in R5)
// ---------------------------------------------------------------------------
__global__ __launch_bounds__(256) void temp_partial(const float* x, const float* Wt,
                                                    float* accbuf) {
    int b = blockIdx.x >> 5, ch = blockIdx.x & 31;
    float a = 0.f;
    for (int si = 0; si < 64; si++) {
        int s = ch * 64 + si;
        const float* xr = x + ((size_t)(b * SS + s)) * DD;
#pragma unroll
        for (int k = 0; k < 4; k++) {
            int c = threadIdx.x + k * 256;
            a += xr[c] * Wt[c];
        }
    }
    for (int o = 32; o; o >>= 1) a += __shfl_xor(a, o);
    __shared__ float red[4];
    if ((threadIdx.x & 63) == 0) red[threadIdx.x >> 6] = a;
    __syncthreads();
    if (threadIdx.x == 0) atomicAdd(&accbuf[b], red[0] + red[1] + red[2] + red[3]);
}

__global__ void temp_final(const float* accbuf, const float* bt, float* itemp) {
    int t = threadIdx.x;
    if (t < BB) {
        float v = accbuf[t] / (float)SS + bt[0];
        float tmp = 1.f / (1.f + __expf(-v)) + 0.5f;
        itemp[t] = 1.f / tmp;
    }
}

// ---------------------------------------------------------------------------
// 3) QKVG GEMM (MFMA): xb[4096,1024] x WT(4 mats) -> Qh bf16 [4096,4096] +bias
// ---------------------------------------------------------------------------
__global__ __launch_bounds__(256) void gemm_qkvg(
        const u16* X, const u16* WT,
        const float* bq, const float* bk, const float* bv, const float* bg, u16* Qh) {
    __shared__ u16 la[64 * 40];
    __shared__ u16 lb[64 * 40];
    int tid = threadIdx.x, wid = tid >> 6, lane = tid & 63;
    int m0 = blockIdx.x * 64, n0 = blockIdx.y * 64;
    int quad = lane >> 4, ml = lane & 15;
    f32x4 acc[4];
#pragma unroll
    for (int i = 0; i < 4; i++) acc[i] = (f32x4){0.f, 0.f, 0.f, 0.f};

    int sr = tid >> 2, sg = tid & 3;
    for (int k0 = 0; k0 < 1024; k0 += 32) {
        __syncthreads();
        *(i32x4*)&la[sr * 40 + sg * 8] = *(const i32x4*)&X[(size_t)(m0 + sr) * 1024 + k0 + sg * 8];
        *(i32x4*)&lb[sr * 40 + sg * 8] = *(const i32x4*)&WT[(size_t)(n0 + sr) * 1024 + k0 + sg * 8];
        __syncthreads();
        bf16x8 a = *(const bf16x8*)&la[(wid * 16 + ml) * 40 + quad * 8];
#pragma unroll
        for (int nt = 0; nt < 4; nt++) {
            bf16x8 bfr = *(const bf16x8*)&lb[(nt * 16 + ml) * 40 + quad * 8];
            acc[nt] = __builtin_amdgcn_mfma_f32_16x16x32_bf16(a, bfr, acc[nt], 0, 0, 0);
        }
    }
#pragma unroll
    for (int nt = 0; nt < 4; nt++) {
        int col = n0 + nt * 16 + ml;
        int mat = col >> 10, bc = col & 1023;
        const float* bp = (mat == 0) ? bq : (mat == 1) ? bk : (mat == 2) ? bv : bg;
        float bias = bp[bc];
#pragma unroll
        for (int r = 0; r < 4; r++) {
            int row = m0 + wid * 16 + quad * 4 + r;
            Qh[(size_t)row * 4096 + col] = f2b(acc[nt][r] + bias);
        }
    }
}

// ---------------------------------------------------------------------------
// 4) normalize q,k -> packed qn,kn [B,H,S,64]; repack v -> vt [B,H,64,S]
// ---------------------------------------------------------------------------
__global__ __launch_bounds__(256) void norm_repack(const u16* Qh, u16* qn, u16* kn, u16* vt) {
    int wid = threadIdx.x >> 6, lane = threadIdx.x & 63;
    int idx = blockIdx.x * 4 + wid;          // (token, head), 65536 total
    int token = idx >> 4, h = idx & 15;
    int b = token >> 11, s = token & 2047;
    int bh = b * HH + h;
    const u16* rowp = Qh + (size_t)token * 4096 + h * 64;
    float q = b2f(rowp[lane]);
    float k = b2f(rowp[1024 + lane]);
    u16 v = rowp[2048 + lane];
    float sq = q * q, sk = k * k;
    for (int o = 32; o; o >>= 1) { sq += __shfl_xor(sq, o); sk += __shfl_xor(sk, o); }
    float qd = fmaxf(sqrtf(sq), 1e-12f), kd = fmaxf(sqrtf(sk), 1e-12f);
    qn[((size_t)bh * SS + s) * DH + lane] = f2b(q / qd);
    kn[((size_t)bh * SS + s) * DH + lane] = f2b(k / kd);
    vt[((size_t)bh * DH + lane) * SS + s] = v;
}

// ---------------------------------------------------------------------------
// 5) attention: block = (b,h,16 q rows). Direct-from-global MFMA B-fragments;
//    scores bf16 in LDS. Top-512 via two-level 256-bin LDS radix histogram
//    (u16-pair packed, 4 sub-copies/wave) — no serial bit-search chains.
// ---------------------------------------------------------------------------
#define EST 2088   // u16 stride: (EST/2)%32==20 -> b128 A-frag reads spread all 32 banks

__global__ __launch_bounds__(256, 2) void attn_kernel(
        const u16* qn, const u16* kn, const u16* vt, const float* itemp, u16* ao) {
    __shared__ __align__(16) u16 e16[16 * EST];   // 66816 B
    __shared__ unsigned whist[16][128];           // 8192 B: wave w -> rows 4w..4w+3 (4 copies)
    __shared__ float zrow_s[16];

    int tid = threadIdx.x, wid = tid >> 6, lane = tid & 63;
    int quad = lane >> 4, nl = lane & 15;
    int bh = blockIdx.x >> 7, qt = blockIdx.x & 127;
    int b = bh >> 4, h = bh & 15;
    const u16* qbase = qn + ((size_t)bh * SS + qt * 16) * DH;
    const u16* kbase = kn + (size_t)bh * SS * DH;
    const u16* vbase = vt + (size_t)bh * DH * SS;
    float it = itemp[b];

    // q A-fragments: lane holds q[m=nl][k=quad*8+j (+32)]
    bf16x8 aq0 = *(const bf16x8*)(qbase + nl * DH + quad * 8);
    bf16x8 aq1 = *(const bf16x8*)(qbase + nl * DH + 32 + quad * 8);

    // ---- scores: barrier-free; wave wid covers cols wid*16+nl (mod 64) ----
#pragma unroll 4
    for (int c = 0; c < 32; c++) {
        int j = c * 64 + wid * 16 + nl;
        const u16* kr = kbase + (size_t)j * DH;
        bf16x8 b0 = *(const bf16x8*)(kr + quad * 8);
        bf16x8 b1 = *(const bf16x8*)(kr + 32 + quad * 8);
        f32x4 acc = (f32x4){0.f, 0.f, 0.f, 0.f};
        acc = __builtin_amdgcn_mfma_f32_16x16x32_bf16(aq0, b0, acc, 0, 0, 0);
        acc = __builtin_amdgcn_mfma_f32_16x16x32_bf16(aq1, b1, acc, 0, 0, 0);
#pragma unroll
        for (int r = 0; r < 4; r++) e16[(quad * 4 + r) * EST + j] = f2b(acc[r] * it);
    }
    __syncthreads();

    // ---- per-wave top-512 via two-level radix histogram (4 rows/wave) ----
    unsigned* wh = &whist[wid * 4][0];            // 512 words private to this wave
    unsigned* myh = wh + (lane & 3) * 128;        // this lane's sub-copy
    for (int rr = 0; rr < 4; rr++) {
        int row = wid * 4 + rr;
#pragma unroll
        for (int i = 0; i < 8; i++) wh[lane + 64 * i] = 0u;
        float s[32];
        int key[32];
#pragma unroll
        for (int c = 0; c < 32; c++) {
            u16 raw = e16[row * EST + c * 64 + lane];
            key[c] = (raw & 0x8000) ? (int)(raw ^ 0xFFFFu) : (int)(raw | 0x8000u);
            s[c] = b2f(raw);
        }
        __syncthreads();
        // level-1: histogram of key>>8 (u16 pair packed; counts <= 2048, no carry)
#pragma unroll
        for (int c = 0; c < 32; c++) {
            int bin = key[c] >> 8;
            atomicAdd(&myh[bin >> 1], (bin & 1) ? 65536u : 1u);
        }
        __syncthreads();
        unsigned c0 = 0, c1 = 0, c2 = 0, c3 = 0;   // lane owns bins 4*lane..4*lane+3
#pragma unroll
        for (int cp = 0; cp < 4; cp++) {
            unsigned w0 = wh[cp * 128 + 2 * lane];
            unsigned w1 = wh[cp * 128 + 2 * lane + 1];
            c0 += w0 & 0xFFFFu; c1 += w0 >> 16;
            c2 += w1 & 0xFFFFu; c3 += w1 >> 16;
        }
        unsigned suf = c0 + c1 + c2 + c3;
#pragma unroll
        for (int o = 1; o < 64; o <<= 1) {
            unsigned t = __shfl_down(suf, o);
            suf += (lane + o < 64) ? t : 0u;
        }
        unsigned S0 = suf, S1 = suf - c0, S2 = S1 - c1, S3 = S2 - c2;
        int lb = -1;
        if (S3 >= (unsigned)KK) lb = 4 * lane + 3;
        else if (S2 >= (unsigned)KK) lb = 4 * lane + 2;
        else if (S1 >= (unsigned)KK) lb = 4 * lane + 1;
        else if (S0 >= (unsigned)KK) lb = 4 * lane;
#pragma unroll
        for (int o = 32; o; o >>= 1) { int t = __shfl_xor(lb, o); lb = (t > lb) ? t : lb; }
        int bstar = lb;
        int sel = bstar & 3;
        unsigned cb = (sel == 0) ? c0 : (sel == 1) ? c1 : (sel == 2) ? c2 : c3;
        unsigned Sb = (sel == 0) ? S0 : (sel == 1) ? S1 : (sel == 2) ? S2 : S3;
        unsigned nd2 = (unsigned)KK - (Sb - cb);            // valid on owner lane
        nd2 = (unsigned)__shfl((int)nd2, bstar >> 2);
        // level-2: histogram of key&255 within bin bstar
#pragma unroll
        for (int i = 0; i < 8; i++) wh[lane + 64 * i] = 0u;
        __syncthreads();
#pragma unroll
        for (int c = 0; c < 32; c++) {
            if ((key[c] >> 8) == bstar) {
                int lo = key[c] & 255;
                atomicAdd(&myh[lo >> 1], (lo & 1) ? 65536u : 1u);
            }
        }
        __syncthreads();
        c0 = c1 = c2 = c3 = 0;
#pragma unroll
        for (int cp = 0; cp < 4; cp++) {
            unsigned w0 = wh[cp * 128 + 2 * lane];
            unsigned w1 = wh[cp * 128 + 2 * lane + 1];
            c0 += w0 & 0xFFFFu; c1 += w0 >> 16;
            c2 += w1 & 0xFFFFu; c3 += w1 >> 16;
        }
        suf = c0 + c1 + c2 + c3;
#pragma unroll
        for (int o = 1; o < 64; o <<= 1) {
            unsigned t = __shfl_down(suf, o);
            suf += (lane + o < 64) ? t : 0u;
        }
        S0 = suf; S1 = suf - c0; S2 = S1 - c1; S3 = S2 - c2;
        lb = -1;
        if (S3 >= nd2) lb = 4 * lane + 3;
        else if (S2 >= nd2) lb = 4 * lane + 2;
        else if (S1 >= nd2) lb = 4 * lane + 1;
        else if (S0 >= nd2) lb = 4 * lane;
#pragma unroll
        for (int o = 32; o; o >>= 1) { int t = __shfl_xor(lb, o); lb = (t > lb) ? t : lb; }
        int P = (bstar << 8) | lb;
        // ---- exp (m=0: |s| < ~2.02, no overflow) + Z, write weights back ----
        float z = 0.f;
#pragma unroll
        for (int c = 0; c < 32; c++) {
            float e = (key[c] >= P) ? __expf(s[c]) : 0.f;
            z += e;
            e16[row * EST + c * 64 + lane] = f2b(e);
        }
#pragma unroll
        for (int o = 32; o; o >>= 1) z += __shfl_xor(z, o);
        if (lane == 0) zrow_s[row] = z;
    }
    __syncthreads();

    // ---- PV: out[16q][64dh] = E[16,2048] x V[2048,64]; barrier-free ----
    f32x4 accp = (f32x4){0.f, 0.f, 0.f, 0.f};
    const u16* vrow = vbase + (size_t)(wid * 16 + nl) * SS;   // dh = wid*16+nl
#pragma unroll 4
    for (int c = 0; c < 32; c++) {
        int j0 = c * 64;
#pragma unroll
        for (int ks = 0; ks < 2; ks++) {
            bf16x8 a = *(const bf16x8*)&e16[nl * EST + j0 + ks * 32 + quad * 8];
            bf16x8 bfr = *(const bf16x8*)(vrow + j0 + ks * 32 + quad * 8);
            accp = __builtin_amdgcn_mfma_f32_16x16x32_bf16(a, bfr, accp, 0, 0, 0);
        }
    }

    // ---- epilogue: scale by 1/Z, write ao bf16 [B,S,H,dh] ----
    {
        int dh = wid * 16 + nl;
#pragma unroll
        for (int r = 0; r < 4; r++) {
            int q = quad * 4 + r;
            float val = accp[r] / zrow_s[q];
            size_t row = (size_t)(b * SS + qt * 16 + q);
            ao[row * DD + h * 64 + dh] = f2b(val);
        }
    }
}

// ---------------------------------------------------------------------------
// 6) out = attn_out @ Wo + bo, highway: gate*out + (1-gate)*x -> fp32
// ---------------------------------------------------------------------------
__global__ __launch_bounds__(256) void gemm_out(
        const u16* AO, const u16* WTo, const float* bo,
        const u16* Qh, const float* x, float* out) {
    __shared__ u16 la[64 * 40];
    __shared__ u16 lb[64 * 40];
    int tid = threadIdx.x, wid = tid >> 6, lane = tid & 63;
    int m0 = blockIdx.x * 64, n0 = blockIdx.y * 64;
    int quad = lane >> 4, ml = lane & 15;
    f32x4 acc[4];
#pragma unroll
    for (int i = 0; i < 4; i++) acc[i] = (f32x4){0.f, 0.f, 0.f, 0.f};

    int sr = tid >> 2, sg = tid & 3;
    for (int k0 = 0; k0 < 1024; k0 += 32) {
        __syncthreads();
        *(i32x4*)&la[sr * 40 + sg * 8] = *(const i32x4*)&AO[(size_t)(m0 + sr) * 1024 + k0 + sg * 8];
        *(i32x4*)&lb[sr * 40 + sg * 8] = *(const i32x4*)&WTo[(size_t)(n0 + sr) * 1024 + k0 + sg * 8];
        __syncthreads();
        bf16x8 a = *(const bf16x8*)&la[(wid * 16 + ml) * 40 + quad * 8];
#pragma unroll
        for (int nt = 0; nt < 4; nt++) {
            bf16x8 bfr = *(const bf16x8*)&lb[(nt * 16 + ml) * 40 + quad * 8];
            acc[nt] = __builtin_amdgcn_mfma_f32_16x16x32_bf16(a, bfr, acc[nt], 0, 0, 0);
        }
    }
#pragma unroll
    for (int nt = 0; nt < 4; nt++) {
        int col = n0 + nt * 16 + ml;
        float bias = bo[col];
#pragma unroll
        for (int r = 0; r < 4; r++) {
            int row = m0 + wid * 16 + quad * 4 + r;
            float g = b2f(Qh[(size_t)row * 4096 + 3072 + col]);
            float gate = 1.f / (1.f + __expf(-g));
            float xv = x[(size_t)row * 1024 + col];
            float o = acc[nt][r] + bias;
            out[(size_t)row * 1024 + col] = gate * o + (1.f - gate) * xv;
        }
    }
}

// ---------------------------------------------------------------------------
extern "C" void kernel_launch(void* const* d_in, const int* in_sizes, int n_in,
                              void* d_out, int out_size, void* d_ws, size_t ws_size,
                              hipStream_t stream) {
    const float* x  = (const float*)d_in[0];
    const float* Wq = (const float*)d_in[1];
    const float* bq = (const float*)d_in[2];
    const float* Wk = (const float*)d_in[3];
    const float* bk = (const float*)d_in[4];
    const float* Wv = (const float*)d_in[5];
    const float* bv = (const float*)d_in[6];
    const float* Wo = (const float*)d_in[7];
    const float* bo = (const float*)d_in[8];
    const float* Wt = (const float*)d_in[9];
    const float* bt = (const float*)d_in[10];
    const float* Wg = (const float*)d_in[11];
    const float* bg = (const float*)d_in[12];

    char* w = (char*)d_ws;
    float* accbuf = (float*)(w + OFF_SCAL);
    float* itemp  = accbuf + 2;
    u16*   WT     = (u16*)(w + OFF_WT);
    u16*   xb     = (u16*)(w + OFF_XB);
    u16*   ao     = (u16*)(w + OFF_AO);   // aliases xb (disjoint lifetime)
    u16*   Qh     = (u16*)(w + OFF_QH);
    u16*   qn     = (u16*)(w + OFF_QN);
    u16*   kn     = (u16*)(w + OFF_KN);
    u16*   vt     = (u16*)(w + OFF_VT);

    hipMemsetAsync(accbuf, 0, 2 * sizeof(float), stream);

    convert_x<<<4096, 256, 0, stream>>>(x, xb);
    transpose_w<<<dim3(16, 16, 5), 256, 0, stream>>>(Wq, Wk, Wv, Wg, Wo, WT);
    temp_partial<<<64, 256, 0, stream>>>(x, Wt, accbuf);
    temp_final<<<1, 64, 0, stream>>>(accbuf, bt, itemp);
    gemm_qkvg<<<dim3(64, 64), 256, 0, stream>>>(xb, WT, bq, bk, bv, bg, Qh);
    norm_repack<<<16384, 256, 0, stream>>>(Qh, qn, kn, vt);
    attn_kernel<<<4096, 256, 0, stream>>>(qn, kn, vt, itemp, ao);
    gemm_out<<<dim3(64, 16), 256, 0, stream>>>(ao, WT + (size_t)4 * 1024 * 1024, bo, Qh, x,
                                               (float*)d_out);
}

// Round 9
// 586.684 us; speedup vs baseline: 9.1407x; 1.0765x over previous
//
#include <hip/hip_runtime.h>

typedef unsigned short u16;
typedef __attribute__((ext_vector_type(4))) float f32x4;
typedef __attribute__((ext_vector_type(8))) short bf16x8;
typedef __attribute__((ext_vector_type(4))) int i32x4;

#define BB 2
#define SS 2048
#define DD 1024
#define HH 16
#define DH 64
#define KK 512

// workspace layout (bytes) — total ~77.2 MB (<= 80.1 MB proven safe in R5)
#define OFF_SCAL  ((size_t)0)                       // accbuf[2] f32, itemp[2] f32
#define OFF_WT    ((size_t)256)                     // 5 x 1024x1024 bf16 [n][k] = 10 MB
#define OFF_XB    (OFF_WT + (size_t)5*1024*1024*2)  // x bf16 [4096][1024] = 8 MB (aliases AO)
#define OFF_AO    OFF_XB                            // attn out bf16 [4096][1024] = 8 MB
#define OFF_QH    (OFF_XB + (size_t)4096*1024*2)    // Qh bf16 [4096][4096] = 32 MB
#define OFF_QN    (OFF_QH + (size_t)4096*4096*2)    // qn bf16 [B,H,S,64] = 8 MB
#define OFF_KN    (OFF_QN + (size_t)4096*1024*2)    // kn bf16 [B,H,S,64] = 8 MB
#define OFF_VT    (OFF_KN + (size_t)4096*1024*2)    // vt bf16 [B,H,64,S] = 8 MB

__device__ __forceinline__ float b2f(u16 u) { return __uint_as_float(((unsigned)u) << 16); }
__device__ __forceinline__ u16 f2b(float f) {
    unsigned u = __float_as_uint(f);
    return (u16)((u + 0x7fffu + ((u >> 16) & 1u)) >> 16);   // RNE
}

// ---------------------------------------------------------------------------
// 0) convert x fp32 -> bf16
// ---------------------------------------------------------------------------
__global__ __launch_bounds__(256) void convert_x(const float* x, u16* xb) {
    int i = (blockIdx.x * 256 + threadIdx.x) * 4;
    float4 v = *(const float4*)(x + i);
    u16 r0 = f2b(v.x), r1 = f2b(v.y), r2 = f2b(v.z), r3 = f2b(v.w);
    xb[i] = r0; xb[i + 1] = r1; xb[i + 2] = r2; xb[i + 3] = r3;
}

// ---------------------------------------------------------------------------
// 1) transpose+convert the five 1024x1024 fp32 weights into WT bf16 [n][k]
// ---------------------------------------------------------------------------
__global__ __launch_bounds__(256) void transpose_w(
        const float* Wq, const float* Wk, const float* Wv, const float* Wg, const float* Wo,
        u16* WT) {
    int z = blockIdx.z;
    const float* src = (z == 0) ? Wq : (z == 1) ? Wk : (z == 2) ? Wv : (z == 3) ? Wg : Wo;
    u16* dst = WT + (size_t)z * 1024 * 1024;
    __shared__ float tile[64][65];
    int n0 = blockIdx.x * 64, k0 = blockIdx.y * 64;
    int rbase = threadIdx.x >> 6, c = threadIdx.x & 63;
#pragma unroll
    for (int i = 0; i < 16; i++) {
        int r = i * 4 + rbase;
        tile[r][c] = src[(size_t)(k0 + r) * 1024 + n0 + c];
    }
    __syncthreads();
#pragma unroll
    for (int i = 0; i < 16; i++) {
        int r = i * 4 + rbase;
        dst[(size_t)(n0 + r) * 1024 + k0 + c] = f2b(tile[c][r]);
    }
}

// ---------------------------------------------------------------------------
// 2) adaptive temperature (fp32, validated in R5)
// ---------------------------------------------------------------------------
__global__ __launch_bounds__(256) void temp_partial(const float* x, const float* Wt,
                                                    float* accbuf) {
    int b = blockIdx.x >> 5, ch = blockIdx.x & 31;
    float a = 0.f;
    for (int si = 0; si < 64; si++) {
        int s = ch * 64 + si;
        const float* xr = x + ((size_t)(b * SS + s)) * DD;
#pragma unroll
        for (int k = 0; k < 4; k++) {
            int c = threadIdx.x + k * 256;
            a += xr[c] * Wt[c];
        }
    }
    for (int o = 32; o; o >>= 1) a += __shfl_xor(a, o);
    __shared__ float red[4];
    if ((threadIdx.x & 63) == 0) red[threadIdx.x >> 6] = a;
    __syncthreads();
    if (threadIdx.x == 0) atomicAdd(&accbuf[b], red[0] + red[1] + red[2] + red[3]);
}

__global__ void temp_final(const float* accbuf, const float* bt, float* itemp) {
    int t = threadIdx.x;
    if (t < BB) {
        float v = accbuf[t] / (float)SS + bt[0];
        float tmp = 1.f / (1.f + __expf(-v)) + 0.5f;
        itemp[t] = 1.f / tmp;
    }
}

// ---------------------------------------------------------------------------
// 3) QKVG GEMM (MFMA): xb[4096,1024] x WT(4 mats) -> Qh bf16 [4096,4096] +bias
// ---------------------------------------------------------------------------
__global__ __launch_bounds__(256) void gemm_qkvg(
        const u16* X, const u16* WT,
        const float* bq, const float* bk, const float* bv, const float* bg, u16* Qh) {
    __shared__ u16 la[64 * 40];
    __shared__ u16 lb[64 * 40];
    int tid = threadIdx.x, wid = tid >> 6, lane = tid & 63;
    int m0 = blockIdx.x * 64, n0 = blockIdx.y * 64;
    int quad = lane >> 4, ml = lane & 15;
    f32x4 acc[4];
#pragma unroll
    for (int i = 0; i < 4; i++) acc[i] = (f32x4){0.f, 0.f, 0.f, 0.f};

    int sr = tid >> 2, sg = tid & 3;
    for (int k0 = 0; k0 < 1024; k0 += 32) {
        __syncthreads();
        *(i32x4*)&la[sr * 40 + sg * 8] = *(const i32x4*)&X[(size_t)(m0 + sr) * 1024 + k0 + sg * 8];
        *(i32x4*)&lb[sr * 40 + sg * 8] = *(const i32x4*)&WT[(size_t)(n0 + sr) * 1024 + k0 + sg * 8];
        __syncthreads();
        bf16x8 a = *(const bf16x8*)&la[(wid * 16 + ml) * 40 + quad * 8];
#pragma unroll
        for (int nt = 0; nt < 4; nt++) {
            bf16x8 bfr = *(const bf16x8*)&lb[(nt * 16 + ml) * 40 + quad * 8];
            acc[nt] = __builtin_amdgcn_mfma_f32_16x16x32_bf16(a, bfr, acc[nt], 0, 0, 0);
        }
    }
#pragma unroll
    for (int nt = 0; nt < 4; nt++) {
        int col = n0 + nt * 16 + ml;
        int mat = col >> 10, bc = col & 1023;
        const float* bp = (mat == 0) ? bq : (mat == 1) ? bk : (mat == 2) ? bv : bg;
        float bias = bp[bc];
#pragma unroll
        for (int r = 0; r < 4; r++) {
            int row = m0 + wid * 16 + quad * 4 + r;
            Qh[(size_t)row * 4096 + col] = f2b(acc[nt][r] + bias);
        }
    }
}

// ---------------------------------------------------------------------------
// 4) normalize q,k -> packed qn,kn [B,H,S,64]; repack v -> vt [B,H,64,S]
// ---------------------------------------------------------------------------
__global__ __launch_bounds__(256) void norm_repack(const u16* Qh, u16* qn, u16* kn, u16* vt) {
    int wid = threadIdx.x >> 6, lane = threadIdx.x & 63;
    int idx = blockIdx.x * 4 + wid;          // (token, head), 65536 total
    int token = idx >> 4, h = idx & 15;
    int b = token >> 11, s = token & 2047;
    int bh = b * HH + h;
    const u16* rowp = Qh + (size_t)token * 4096 + h * 64;
    float q = b2f(rowp[lane]);
    float k = b2f(rowp[1024 + lane]);
    u16 v = rowp[2048 + lane];
    float sq = q * q, sk = k * k;
    for (int o = 32; o; o >>= 1) { sq += __shfl_xor(sq, o); sk += __shfl_xor(sk, o); }
    float qd = fmaxf(sqrtf(sq), 1e-12f), kd = fmaxf(sqrtf(sk), 1e-12f);
    qn[((size_t)bh * SS + s) * DH + lane] = f2b(q / qd);
    kn[((size_t)bh * SS + s) * DH + lane] = f2b(k / kd);
    vt[((size_t)bh * DH + lane) * SS + s] = v;
}

// ---------------------------------------------------------------------------
// 5) attention: 512 threads / 8 waves per block = (b,h,16 q rows).
//    Scores: 8 waves x 16 col-chunks, direct-from-global B-frags, bf16 to LDS.
//    Select: per-wave 16-bit bit-search with ballot+popcount (no LDS atomics,
//    no shfl chains, no barriers). PV: waves split K in halves, LDS combine.
// ---------------------------------------------------------------------------
#define EST 2088   // u16 stride: (EST/2)%32==20 -> b128 A-frag reads spread all 32 banks

__global__ __launch_bounds__(512, 4) void attn_kernel(
        const u16* qn, const u16* kn, const u16* vt, const float* itemp, u16* ao) {
    __shared__ __align__(16) u16 e16[16 * EST];   // 66816 B
    __shared__ float pvp[16 * 65];                // 4160 B partial PV (padded)
    __shared__ float zrow_s[16];

    int tid = threadIdx.x, wid = tid >> 6, lane = tid & 63;
    int quad = lane >> 4, nl = lane & 15;
    int bh = blockIdx.x >> 7, qt = blockIdx.x & 127;
    int b = bh >> 4, h = bh & 15;
    const u16* qbase = qn + ((size_t)bh * SS + qt * 16) * DH;
    const u16* kbase = kn + (size_t)bh * SS * DH;
    const u16* vbase = vt + (size_t)bh * DH * SS;
    float it = itemp[b];

    // q A-fragments: lane holds q[m=nl][k=quad*8+j (+32)]
    bf16x8 aq0 = *(const bf16x8*)(qbase + nl * DH + quad * 8);
    bf16x8 aq1 = *(const bf16x8*)(qbase + nl * DH + 32 + quad * 8);

    // ---- scores: wave wid covers cols wid*16+nl (mod 128), 16 chunks ----
#pragma unroll 4
    for (int c = 0; c < 16; c++) {
        int j = c * 128 + wid * 16 + nl;
        const u16* kr = kbase + (size_t)j * DH;
        bf16x8 b0 = *(const bf16x8*)(kr + quad * 8);
        bf16x8 b1 = *(const bf16x8*)(kr + 32 + quad * 8);
        f32x4 acc = (f32x4){0.f, 0.f, 0.f, 0.f};
        acc = __builtin_amdgcn_mfma_f32_16x16x32_bf16(aq0, b0, acc, 0, 0, 0);
        acc = __builtin_amdgcn_mfma_f32_16x16x32_bf16(aq1, b1, acc, 0, 0, 0);
#pragma unroll
        for (int r = 0; r < 4; r++) e16[(quad * 4 + r) * EST + j] = f2b(acc[r] * it);
    }
    __syncthreads();

    // ---- select: wave wid owns rows 2*wid, 2*wid+1; ballot+popcount search --
    for (int rr = 0; rr < 2; rr++) {
        int row = wid * 2 + rr;
        int key[32];
#pragma unroll
        for (int c = 0; c < 32; c++) {
            int raw = (int)e16[row * EST + c * 64 + lane];
            key[c] = (raw & 0x8000) ? (raw ^ 0xFFFF) : (raw | 0x8000);
        }
        int P = 0;
        for (int bit = 15; bit >= 0; bit--) {
            int cand = P | (1 << bit);
            int cnt = 0;
#pragma unroll
            for (int c = 0; c < 32; c++)
                cnt += (int)__popcll(__ballot(key[c] >= cand));
            if (cnt >= KK) P = cand;
        }
        // exp (m=0: |s| < ~2.02, no overflow) + Z, write weights back
        float z = 0.f;
#pragma unroll
        for (int c = 0; c < 32; c++) {
            float e = 0.f;
            if (key[c] >= P) {
                int raw = (key[c] & 0x8000) ? (key[c] ^ 0x8000) : (key[c] ^ 0xFFFF);
                e = __expf(b2f((u16)raw));
            }
            z += e;
            e16[row * EST + c * 64 + lane] = f2b(e);
        }
#pragma unroll
        for (int o = 32; o; o >>= 1) z += __shfl_xor(z, o);
        if (lane == 0) zrow_s[row] = z;
    }
    __syncthreads();

    // ---- PV: waves 0-3 cols 0..1023, waves 4-7 cols 1024..2047 ----
    f32x4 accp = (f32x4){0.f, 0.f, 0.f, 0.f};
    int kHalf = (wid >> 2) * 1024;
    int dh = (wid & 3) * 16 + nl;
    const u16* vrow = vbase + (size_t)dh * SS;
#pragma unroll 4
    for (int c = 0; c < 16; c++) {
        int j0 = kHalf + c * 64;
#pragma unroll
        for (int ks = 0; ks < 2; ks++) {
            bf16x8 a = *(const bf16x8*)&e16[nl * EST + j0 + ks * 32 + quad * 8];
            bf16x8 bfr = *(const bf16x8*)(vrow + j0 + ks * 32 + quad * 8);
            accp = __builtin_amdgcn_mfma_f32_16x16x32_bf16(a, bfr, accp, 0, 0, 0);
        }
    }
    if (wid >= 4) {
#pragma unroll
        for (int r = 0; r < 4; r++) pvp[(quad * 4 + r) * 65 + dh] = accp[r];
    }
    __syncthreads();
    if (wid < 4) {
#pragma unroll
        for (int r = 0; r < 4; r++) {
            int q = quad * 4 + r;
            float val = (accp[r] + pvp[q * 65 + dh]) / zrow_s[q];
            size_t row = (size_t)(b * SS + qt * 16 + q);
            ao[row * DD + h * 64 + dh] = f2b(val);
        }
    }
}

// ---------------------------------------------------------------------------
// 6) out = attn_out @ Wo + bo, highway: gate*out + (1-gate)*x -> fp32
// ---------------------------------------------------------------------------
__global__ __launch_bounds__(256) void gemm_out(
        const u16* AO, const u16* WTo, const float* bo,
        const u16* Qh, const float* x, float* out) {
    __shared__ u16 la[64 * 40];
    __shared__ u16 lb[64 * 40];
    int tid = threadIdx.x, wid = tid >> 6, lane = tid & 63;
    int m0 = blockIdx.x * 64, n0 = blockIdx.y * 64;
    int quad = lane >> 4, ml = lane & 15;
    f32x4 acc[4];
#pragma unroll
    for (int i = 0; i < 4; i++) acc[i] = (f32x4){0.f, 0.f, 0.f, 0.f};

    int sr = tid >> 2, sg = tid & 3;
    for (int k0 = 0; k0 < 1024; k0 += 32) {
        __syncthreads();
        *(i32x4*)&la[sr * 40 + sg * 8] = *(const i32x4*)&AO[(size_t)(m0 + sr) * 1024 + k0 + sg * 8];
        *(i32x4*)&lb[sr * 40 + sg * 8] = *(const i32x4*)&WTo[(size_t)(n0 + sr) * 1024 + k0 + sg * 8];
        __syncthreads();
        bf16x8 a = *(const bf16x8*)&la[(wid * 16 + ml) * 40 + quad * 8];
#pragma unroll
        for (int nt = 0; nt < 4; nt++) {
            bf16x8 bfr = *(const bf16x8*)&lb[(nt * 16 + ml) * 40 + quad * 8];
            acc[nt] = __builtin_amdgcn_mfma_f32_16x16x32_bf16(a, bfr, acc[nt], 0, 0, 0);
        }
    }
#pragma unroll
    for (int nt = 0; nt < 4; nt++) {
        int col = n0 + nt * 16 + ml;
        float bias = bo[col];
#pragma unroll
        for (int r = 0; r < 4; r++) {
            int row = m0 + wid * 16 + quad * 4 + r;
            float g = b2f(Qh[(size_t)row * 4096 + 3072 + col]);
            float gate = 1.f / (1.f + __expf(-g));
            float xv = x[(size_t)row * 1024 + col];
            float o = acc[nt][r] + bias;
            out[(size_t)row * 1024 + col] = gate * o + (1.f - gate) * xv;
        }
    }
}

// ---------------------------------------------------------------------------
extern "C" void kernel_launch(void* const* d_in, const int* in_sizes, int n_in,
                              void* d_out, int out_size, void* d_ws, size_t ws_size,
                              hipStream_t stream) {
    const float* x  = (const float*)d_in[0];
    const float* Wq = (const float*)d_in[1];
    const float* bq = (const float*)d_in[2];
    const float* Wk = (const float*)d_in[3];
    const float* bk = (const float*)d_in[4];
    const float* Wv = (const float*)d_in[5];
    const float* bv = (const float*)d_in[6];
    const float* Wo = (const float*)d_in[7];
    const float* bo = (const float*)d_in[8];
    const float* Wt = (const float*)d_in[9];
    const float* bt = (const float*)d_in[10];
    const float* Wg = (const float*)d_in[11];
    const float* bg = (const float*)d_in[12];

    char* w = (char*)d_ws;
    float* accbuf = (float*)(w + OFF_SCAL);
    float* itemp  = accbuf + 2;
    u16*   WT     = (u16*)(w + OFF_WT);
    u16*   xb     = (u16*)(w + OFF_XB);
    u16*   ao     = (u16*)(w + OFF_AO);   // aliases xb (disjoint lifetime)
    u16*   Qh     = (u16*)(w + OFF_QH);
    u16*   qn     = (u16*)(w + OFF_QN);
    u16*   kn     = (u16*)(w + OFF_KN);
    u16*   vt     = (u16*)(w + OFF_VT);

    hipMemsetAsync(accbuf, 0, 2 * sizeof(float), stream);

    convert_x<<<4096, 256, 0, stream>>>(x, xb);
    transpose_w<<<dim3(16, 16, 5), 256, 0, stream>>>(Wq, Wk, Wv, Wg, Wo, WT);
    temp_partial<<<64, 256, 0, stream>>>(x, Wt, accbuf);
    temp_final<<<1, 64, 0, stream>>>(accbuf, bt, itemp);
    gemm_qkvg<<<dim3(64, 64), 256, 0, stream>>>(xb, WT, bq, bk, bv, bg, Qh);
    norm_repack<<<16384, 256, 0, stream>>>(Qh, qn, kn, vt);
    attn_kernel<<<4096, 512, 0, stream>>>(qn, kn, vt, itemp, ao);
    gemm_out<<<dim3(64, 16), 256, 0, stream>>>(ao, WT + (size_t)4 * 1024 * 1024, bo, Qh, x,
                                               (float*)d_out);
}

// Round 10
// 548.495 us; speedup vs baseline: 9.7771x; 1.0696x over previous
//
#include <hip/hip_runtime.h>

typedef unsigned short u16;
typedef __attribute__((ext_vector_type(4))) float f32x4;
typedef __attribute__((ext_vector_type(8))) short bf16x8;
typedef __attribute__((ext_vector_type(4))) int i32x4;

#define BB 2
#define SS 2048
#define DD 1024
#define HH 16
#define DH 64
#define KK 512

// workspace layout (bytes) — total ~77.2 MB (<= 80.1 MB proven safe in R5)
#define OFF_SCAL  ((size_t)0)                       // accbuf[2] f32, itemp[2] f32
#define OFF_WT    ((size_t)256)                     // 5 x 1024x1024 bf16 [n][k] = 10 MB
#define OFF_XB    (OFF_WT + (size_t)5*1024*1024*2)  // x bf16 [4096][1024] = 8 MB (aliases AO)
#define OFF_AO    OFF_XB                            // attn out bf16 [4096][1024] = 8 MB
#define OFF_QH    (OFF_XB + (size_t)4096*1024*2)    // Qh bf16 [4096][4096] = 32 MB
#define OFF_QN    (OFF_QH + (size_t)4096*4096*2)    // qn bf16 [B,H,S,64] = 8 MB
#define OFF_KN    (OFF_QN + (size_t)4096*1024*2)    // kn bf16 [B,H,S,64] = 8 MB
#define OFF_VT    (OFF_KN + (size_t)4096*1024*2)    // vt bf16 [B,H,64,S] = 8 MB

__device__ __forceinline__ float b2f(u16 u) { return __uint_as_float(((unsigned)u) << 16); }
__device__ __forceinline__ u16 f2b(float f) {
    unsigned u = __float_as_uint(f);
    return (u16)((u + 0x7fffu + ((u >> 16) & 1u)) >> 16);   // RNE
}

// ---------------------------------------------------------------------------
// 0) convert x fp32 -> bf16
// ---------------------------------------------------------------------------
__global__ __launch_bounds__(256) void convert_x(const float* x, u16* xb) {
    int i = (blockIdx.x * 256 + threadIdx.x) * 4;
    float4 v = *(const float4*)(x + i);
    u16 r0 = f2b(v.x), r1 = f2b(v.y), r2 = f2b(v.z), r3 = f2b(v.w);
    xb[i] = r0; xb[i + 1] = r1; xb[i + 2] = r2; xb[i + 3] = r3;
}

// ---------------------------------------------------------------------------
// 1) transpose+convert the five 1024x1024 fp32 weights into WT bf16 [n][k]
// ---------------------------------------------------------------------------
__global__ __launch_bounds__(256) void transpose_w(
        const float* Wq, const float* Wk, const float* Wv, const float* Wg, const float* Wo,
        u16* WT) {
    int z = blockIdx.z;
    const float* src = (z == 0) ? Wq : (z == 1) ? Wk : (z == 2) ? Wv : (z == 3) ? Wg : Wo;
    u16* dst = WT + (size_t)z * 1024 * 1024;
    __shared__ float tile[64][65];
    int n0 = blockIdx.x * 64, k0 = blockIdx.y * 64;
    int rbase = threadIdx.x >> 6, c = threadIdx.x & 63;
#pragma unroll
    for (int i = 0; i < 16; i++) {
        int r = i * 4 + rbase;
        tile[r][c] = src[(size_t)(k0 + r) * 1024 + n0 + c];
    }
    __syncthreads();
#pragma unroll
    for (int i = 0; i < 16; i++) {
        int r = i * 4 + rbase;
        dst[(size_t)(n0 + r) * 1024 + k0 + c] = f2b(tile[c][r]);
    }
}

// ---------------------------------------------------------------------------
// 2) adaptive temperature (fp32, validated in R5)
// ---------------------------------------------------------------------------
__global__ __launch_bounds__(256) void temp_partial(const float* x, const float* Wt,
                                                    float* accbuf) {
    int b = blockIdx.x >> 5, ch = blockIdx.x & 31;
    float a = 0.f;
    for (int si = 0; si < 64; si++) {
        int s = ch * 64 + si;
        const float* xr = x + ((size_t)(b * SS + s)) * DD;
#pragma unroll
        for (int k = 0; k < 4; k++) {
            int c = threadIdx.x + k * 256;
            a += xr[c] * Wt[c];
        }
    }
    for (int o = 32; o; o >>= 1) a += __shfl_xor(a, o);
    __shared__ float red[4];
    if ((threadIdx.x & 63) == 0) red[threadIdx.x >> 6] = a;
    __syncthreads();
    if (threadIdx.x == 0) atomicAdd(&accbuf[b], red[0] + red[1] + red[2] + red[3]);
}

__global__ void temp_final(const float* accbuf, const float* bt, float* itemp) {
    int t = threadIdx.x;
    if (t < BB) {
        float v = accbuf[t] / (float)SS + bt[0];
        float tmp = 1.f / (1.f + __expf(-v)) + 0.5f;
        itemp[t] = 1.f / tmp;
    }
}

// ---------------------------------------------------------------------------
// 3) QKVG GEMM (MFMA): xb[4096,1024] x WT(4 mats) -> Qh bf16 [4096,4096] +bias
// ---------------------------------------------------------------------------
__global__ __launch_bounds__(256) void gemm_qkvg(
        const u16* X, const u16* WT,
        const float* bq, const float* bk, const float* bv, const float* bg, u16* Qh) {
    __shared__ u16 la[64 * 40];
    __shared__ u16 lb[64 * 40];
    int tid = threadIdx.x, wid = tid >> 6, lane = tid & 63;
    int m0 = blockIdx.x * 64, n0 = blockIdx.y * 64;
    int quad = lane >> 4, ml = lane & 15;
    f32x4 acc[4];
#pragma unroll
    for (int i = 0; i < 4; i++) acc[i] = (f32x4){0.f, 0.f, 0.f, 0.f};

    int sr = tid >> 2, sg = tid & 3;
    for (int k0 = 0; k0 < 1024; k0 += 32) {
        __syncthreads();
        *(i32x4*)&la[sr * 40 + sg * 8] = *(const i32x4*)&X[(size_t)(m0 + sr) * 1024 + k0 + sg * 8];
        *(i32x4*)&lb[sr * 40 + sg * 8] = *(const i32x4*)&WT[(size_t)(n0 + sr) * 1024 + k0 + sg * 8];
        __syncthreads();
        bf16x8 a = *(const bf16x8*)&la[(wid * 16 + ml) * 40 + quad * 8];
#pragma unroll
        for (int nt = 0; nt < 4; nt++) {
            bf16x8 bfr = *(const bf16x8*)&lb[(nt * 16 + ml) * 40 + quad * 8];
            acc[nt] = __builtin_amdgcn_mfma_f32_16x16x32_bf16(a, bfr, acc[nt], 0, 0, 0);
        }
    }
#pragma unroll
    for (int nt = 0; nt < 4; nt++) {
        int col = n0 + nt * 16 + ml;
        int mat = col >> 10, bc = col & 1023;
        const float* bp = (mat == 0) ? bq : (mat == 1) ? bk : (mat == 2) ? bv : bg;
        float bias = bp[bc];
#pragma unroll
        for (int r = 0; r < 4; r++) {
            int row = m0 + wid * 16 + quad * 4 + r;
            Qh[(size_t)row * 4096 + col] = f2b(acc[nt][r] + bias);
        }
    }
}

// ---------------------------------------------------------------------------
// 4) normalize q,k -> packed qn,kn [B,H,S,64]; repack v -> vt [B,H,64,S]
// ---------------------------------------------------------------------------
__global__ __launch_bounds__(256) void norm_repack(const u16* Qh, u16* qn, u16* kn, u16* vt) {
    int wid = threadIdx.x >> 6, lane = threadIdx.x & 63;
    int idx = blockIdx.x * 4 + wid;          // (token, head), 65536 total
    int token = idx >> 4, h = idx & 15;
    int b = token >> 11, s = token & 2047;
    int bh = b * HH + h;
    const u16* rowp = Qh + (size_t)token * 4096 + h * 64;
    float q = b2f(rowp[lane]);
    float k = b2f(rowp[1024 + lane]);
    u16 v = rowp[2048 + lane];
    float sq = q * q, sk = k * k;
    for (int o = 32; o; o >>= 1) { sq += __shfl_xor(sq, o); sk += __shfl_xor(sk, o); }
    float qd = fmaxf(sqrtf(sq), 1e-12f), kd = fmaxf(sqrtf(sk), 1e-12f);
    qn[((size_t)bh * SS + s) * DH + lane] = f2b(q / qd);
    kn[((size_t)bh * SS + s) * DH + lane] = f2b(k / kd);
    vt[((size_t)bh * DH + lane) * SS + s] = v;
}

// ---------------------------------------------------------------------------
// 5) attention: 1024 threads / 16 waves per block = (b,h,16 q rows).
//    Scores: 16 waves x 8 col-chunks (direct-from-global B-frags, bf16->LDS).
//    Select: 1 row PER WAVE, ballot+popcount 16-bit search (no LDS atomics).
//    PV: 16 waves = 4 dh-groups x 4 K-quarters, padded-LDS combine.
//    LDS 79.6 KB -> 2 blocks/CU = 32 waves/CU (100% occupancy target).
// ---------------------------------------------------------------------------
#define EST 2088   // u16 stride: (EST/2)%32==20 -> b128 A-frag reads spread all 32 banks

__global__ __launch_bounds__(1024, 8) void attn_kernel(
        const u16* qn, const u16* kn, const u16* vt, const float* itemp, u16* ao) {
    __shared__ __align__(16) u16 e16[16 * EST];   // 66816 B
    __shared__ float pvp[3][16][66];              // 12672 B PV partials (padded)
    __shared__ float zrow_s[16];

    int tid = threadIdx.x, wid = tid >> 6, lane = tid & 63;   // wid in [0,16)
    int quad = lane >> 4, nl = lane & 15;
    int bh = blockIdx.x >> 7, qt = blockIdx.x & 127;
    int b = bh >> 4, h = bh & 15;
    const u16* qbase = qn + ((size_t)bh * SS + qt * 16) * DH;
    const u16* kbase = kn + (size_t)bh * SS * DH;
    const u16* vbase = vt + (size_t)bh * DH * SS;
    float it = itemp[b];

    // q A-fragments: lane holds q[m=nl][k=quad*8+j (+32)]
    bf16x8 aq0 = *(const bf16x8*)(qbase + nl * DH + quad * 8);
    bf16x8 aq1 = *(const bf16x8*)(qbase + nl * DH + 32 + quad * 8);

    // ---- scores: wave wid covers cols wid*16+nl (mod 256), 8 chunks ----
#pragma unroll 4
    for (int c = 0; c < 8; c++) {
        int j = c * 256 + wid * 16 + nl;
        const u16* kr = kbase + (size_t)j * DH;
        bf16x8 b0 = *(const bf16x8*)(kr + quad * 8);
        bf16x8 b1 = *(const bf16x8*)(kr + 32 + quad * 8);
        f32x4 acc = (f32x4){0.f, 0.f, 0.f, 0.f};
        acc = __builtin_amdgcn_mfma_f32_16x16x32_bf16(aq0, b0, acc, 0, 0, 0);
        acc = __builtin_amdgcn_mfma_f32_16x16x32_bf16(aq1, b1, acc, 0, 0, 0);
#pragma unroll
        for (int r = 0; r < 4; r++) e16[(quad * 4 + r) * EST + j] = f2b(acc[r] * it);
    }
    __syncthreads();

    // ---- select: wave wid owns row wid; ballot+popcount bit search ----
    {
        int row = wid;
        int key[32];
#pragma unroll
        for (int c = 0; c < 32; c++) {
            int raw = (int)e16[row * EST + c * 64 + lane];
            key[c] = (raw & 0x8000) ? (raw ^ 0xFFFF) : (raw | 0x8000);
        }
        int P = 0;
        for (int bit = 15; bit >= 0; bit--) {
            int cand = P | (1 << bit);
            int cnt = 0;
#pragma unroll
            for (int c = 0; c < 32; c++)
                cnt += (int)__popcll(__ballot(key[c] >= cand));
            if (cnt >= KK) P = cand;
        }
        // exp (m=0: |s| < ~2.02, no overflow) + Z, write weights back
        float z = 0.f;
#pragma unroll
        for (int c = 0; c < 32; c++) {
            float e = 0.f;
            if (key[c] >= P) {
                int raw = (key[c] & 0x8000) ? (key[c] ^ 0x8000) : (key[c] ^ 0xFFFF);
                e = __expf(b2f((u16)raw));
            }
            z += e;
            e16[row * EST + c * 64 + lane] = f2b(e);
        }
#pragma unroll
        for (int o = 32; o; o >>= 1) z += __shfl_xor(z, o);
        if (lane == 0) zrow_s[row] = z;
    }
    __syncthreads();

    // ---- PV: wave = (K-quarter kq = wid>>2, dh-group g = wid&3) ----
    f32x4 accp = (f32x4){0.f, 0.f, 0.f, 0.f};
    int kq = wid >> 2, g = wid & 3;
    int dh = g * 16 + nl;
    const u16* vrow = vbase + (size_t)dh * SS;
#pragma unroll 4
    for (int c = 0; c < 8; c++) {
        int j0 = kq * 512 + c * 64;
#pragma unroll
        for (int ks = 0; ks < 2; ks++) {
            bf16x8 a = *(const bf16x8*)&e16[nl * EST + j0 + ks * 32 + quad * 8];
            bf16x8 bfr = *(const bf16x8*)(vrow + j0 + ks * 32 + quad * 8);
            accp = __builtin_amdgcn_mfma_f32_16x16x32_bf16(a, bfr, accp, 0, 0, 0);
        }
    }
    if (kq) {
#pragma unroll
        for (int r = 0; r < 4; r++) pvp[kq - 1][quad * 4 + r][dh] = accp[r];
    }
    __syncthreads();
    if (kq == 0) {
#pragma unroll
        for (int r = 0; r < 4; r++) {
            int q = quad * 4 + r;
            float val = (accp[r] + pvp[0][q][dh] + pvp[1][q][dh] + pvp[2][q][dh]) / zrow_s[q];
            size_t row = (size_t)(b * SS + qt * 16 + q);
            ao[row * DD + h * 64 + dh] = f2b(val);
        }
    }
}

// ---------------------------------------------------------------------------
// 6) out = attn_out @ Wo + bo, highway: gate*out + (1-gate)*x -> fp32
// ---------------------------------------------------------------------------
__global__ __launch_bounds__(256) void gemm_out(
        const u16* AO, const u16* WTo, const float* bo,
        const u16* Qh, const float* x, float* out) {
    __shared__ u16 la[64 * 40];
    __shared__ u16 lb[64 * 40];
    int tid = threadIdx.x, wid = tid >> 6, lane = tid & 63;
    int m0 = blockIdx.x * 64, n0 = blockIdx.y * 64;
    int quad = lane >> 4, ml = lane & 15;
    f32x4 acc[4];
#pragma unroll
    for (int i = 0; i < 4; i++) acc[i] = (f32x4){0.f, 0.f, 0.f, 0.f};

    int sr = tid >> 2, sg = tid & 3;
    for (int k0 = 0; k0 < 1024; k0 += 32) {
        __syncthreads();
        *(i32x4*)&la[sr * 40 + sg * 8] = *(const i32x4*)&AO[(size_t)(m0 + sr) * 1024 + k0 + sg * 8];
        *(i32x4*)&lb[sr * 40 + sg * 8] = *(const i32x4*)&WTo[(size_t)(n0 + sr) * 1024 + k0 + sg * 8];
        __syncthreads();
        bf16x8 a = *(const bf16x8*)&la[(wid * 16 + ml) * 40 + quad * 8];
#pragma unroll
        for (int nt = 0; nt < 4; nt++) {
            bf16x8 bfr = *(const bf16x8*)&lb[(nt * 16 + ml) * 40 + quad * 8];
            acc[nt] = __builtin_amdgcn_mfma_f32_16x16x32_bf16(a, bfr, acc[nt], 0, 0, 0);
        }
    }
#pragma unroll
    for (int nt = 0; nt < 4; nt++) {
        int col = n0 + nt * 16 + ml;
        float bias = bo[col];
#pragma unroll
        for (int r = 0; r < 4; r++) {
            int row = m0 + wid * 16 + quad * 4 + r;
            float g = b2f(Qh[(size_t)row * 4096 + 3072 + col]);
            float gate = 1.f / (1.f + __expf(-g));
            float xv = x[(size_t)row * 1024 + col];
            float o = acc[nt][r] + bias;
            out[(size_t)row * 1024 + col] = gate * o + (1.f - gate) * xv;
        }
    }
}

// ---------------------------------------------------------------------------
extern "C" void kernel_launch(void* const* d_in, const int* in_sizes, int n_in,
                              void* d_out, int out_size, void* d_ws, size_t ws_size,
                              hipStream_t stream) {
    const float* x  = (const float*)d_in[0];
    const float* Wq = (const float*)d_in[1];
    const float* bq = (const float*)d_in[2];
    const float* Wk = (const float*)d_in[3];
    const float* bk = (const float*)d_in[4];
    const float* Wv = (const float*)d_in[5];
    const float* bv = (const float*)d_in[6];
    const float* Wo = (const float*)d_in[7];
    const float* bo = (const float*)d_in[8];
    const float* Wt = (const float*)d_in[9];
    const float* bt = (const float*)d_in[10];
    const float* Wg = (const float*)d_in[11];
    const float* bg = (const float*)d_in[12];

    char* w = (char*)d_ws;
    float* accbuf = (float*)(w + OFF_SCAL);
    float* itemp  = accbuf + 2;
    u16*   WT     = (u16*)(w + OFF_WT);
    u16*   xb     = (u16*)(w + OFF_XB);
    u16*   ao     = (u16*)(w + OFF_AO);   // aliases xb (disjoint lifetime)
    u16*   Qh     = (u16*)(w + OFF_QH);
    u16*   qn     = (u16*)(w + OFF_QN);
    u16*   kn     = (u16*)(w + OFF_KN);
    u16*   vt     = (u16*)(w + OFF_VT);

    hipMemsetAsync(accbuf, 0, 2 * sizeof(float), stream);

    convert_x<<<4096, 256, 0, stream>>>(x, xb);
    transpose_w<<<dim3(16, 16, 5), 256, 0, stream>>>(Wq, Wk, Wv, Wg, Wo, WT);
    temp_partial<<<64, 256, 0, stream>>>(x, Wt, accbuf);
    temp_final<<<1, 64, 0, stream>>>(accbuf, bt, itemp);
    gemm_qkvg<<<dim3(64, 64), 256, 0, stream>>>(xb, WT, bq, bk, bv, bg, Qh);
    norm_repack<<<16384, 256, 0, stream>>>(Qh, qn, kn, vt);
    attn_kernel<<<4096, 1024, 0, stream>>>(qn, kn, vt, itemp, ao);
    gemm_out<<<dim3(64, 16), 256, 0, stream>>>(ao, WT + (size_t)4 * 1024 * 1024, bo, Qh, x,
                                               (float*)d_out);
}